// Round 1
// baseline (4244.247 us; speedup 1.0000x reference)
//
#include <hip/hip_runtime.h>
#include <stdint.h>
#include <math.h>

// ---------- types ----------
typedef __attribute__((ext_vector_type(8))) short bf16x8;   // 8 bf16 (4 VGPR)
typedef __attribute__((ext_vector_type(4))) short bf16x4;
typedef __attribute__((ext_vector_type(4))) float f32x4;

__device__ __forceinline__ short f2bf(float f) {
  unsigned u = __builtin_bit_cast(unsigned, f);
  unsigned r = u + 0x7fffu + ((u >> 16) & 1u);
  return (short)(r >> 16);
}

__device__ __forceinline__ f32x4 mfma16(bf16x8 a, bf16x8 b, f32x4 c) {
  return __builtin_amdgcn_mfma_f32_16x16x32_bf16(a, b, c, 0, 0, 0);
}

// LDS tile index: row-major [rows][64] bf16, 16B-block XOR swizzle on row&7.
// col must be a multiple of 4. Preserves 8B/16B alignment.
__device__ __forceinline__ int swz(int row, int col) {
  return row * 64 + (((col >> 3) ^ (row & 7)) << 3) + (col & 7);
}

// ---------- embedding ----------
__global__ __launch_bounds__(256) void embed_k(const int* __restrict__ ids,
                                               const float* __restrict__ tok,
                                               const float* __restrict__ pos,
                                               float* __restrict__ x) {
  int row = blockIdx.x, t = threadIdx.x;
  int id = ids[row];
  const float4 a = *reinterpret_cast<const float4*>(tok + (size_t)id * 1024 + t * 4);
  const float4 b = *reinterpret_cast<const float4*>(pos + (size_t)row * 1024 + t * 4);
  float4 o = make_float4(a.x + b.x, a.y + b.y, a.z + b.z, a.w + b.w);
  *reinterpret_cast<float4*>(x + (size_t)row * 1024 + t * 4) = o;
}

// ---------- layernorm (f32 in, bf16 out) ----------
__global__ __launch_bounds__(256) void ln_k(const float* __restrict__ x,
                                            const float* __restrict__ gw,
                                            const float* __restrict__ bw,
                                            short* __restrict__ out) {
  int row = blockIdx.x, t = threadIdx.x;
  const float4 v = *reinterpret_cast<const float4*>(x + (size_t)row * 1024 + t * 4);
  float s = v.x + v.y + v.z + v.w;
  float q = v.x * v.x + v.y * v.y + v.z * v.z + v.w * v.w;
#pragma unroll
  for (int o = 32; o > 0; o >>= 1) { s += __shfl_xor(s, o); q += __shfl_xor(q, o); }
  __shared__ float sh[8];
  int w = t >> 6;
  if ((t & 63) == 0) { sh[w] = s; sh[4 + w] = q; }
  __syncthreads();
  float ts = sh[0] + sh[1] + sh[2] + sh[3];
  float tq = sh[4] + sh[5] + sh[6] + sh[7];
  float mean = ts * (1.f / 1024.f);
  float var  = tq * (1.f / 1024.f) - mean * mean;
  float rstd = rsqrtf(var + 1e-5f);
  const float4 gv = *reinterpret_cast<const float4*>(gw + t * 4);
  const float4 bv = *reinterpret_cast<const float4*>(bw + t * 4);
  bf16x4 ov = { f2bf((v.x - mean) * rstd * gv.x + bv.x),
                f2bf((v.y - mean) * rstd * gv.y + bv.y),
                f2bf((v.z - mean) * rstd * gv.z + bv.z),
                f2bf((v.w - mean) * rstd * gv.w + bv.w) };
  *reinterpret_cast<bf16x4*>(out + (size_t)row * 1024 + t * 4) = ov;
}

// ---------- GEMM: C[M,N] = A_bf16[M,K] @ W_f32[K,N] (+bias, epilogue) ----------
// EPI: 0 = bf16 out, (acc+bias)*scale   (QKV projections)
//      1 = bf16 out, exact GELU(acc+bias)
//      2 = f32 out,  resid + acc + bias (residual add, in-place on resid)
//      3 = f32 out,  acc (head, no bias)
template <int EPI>
__global__ __launch_bounds__(256)
void gemm_k(const short* __restrict__ A, const float* __restrict__ W,
            const float* __restrict__ bias, const float* resid, void* out,
            int M, int N, int K, float scale) {
  __shared__ short As[128 * 64];  // A tile  [m][k] swizzled
  __shared__ short Bs[128 * 64];  // W tileT [n][k] swizzled
  const int t = threadIdx.x;
  const int lane = t & 63;
  const int g = lane >> 4, r = lane & 15;
  const int wid = t >> 6, wr = wid >> 1, wc = wid & 1;
  const int m0 = blockIdx.y * 128, n0 = blockIdx.x * 128;

  f32x4 acc[4][4];
#pragma unroll
  for (int i = 0; i < 4; ++i)
#pragma unroll
    for (int j = 0; j < 4; ++j) { f32x4 z = {0.f, 0.f, 0.f, 0.f}; acc[i][j] = z; }

  const int arow = t >> 3, ac = t & 7;  // A staging: row arow+32p, 16B chunk ac
  const int bnn = t >> 1, bkh = t & 1;  // B staging: n col bnn, k-group half bkh

  for (int k0 = 0; k0 < K; k0 += 64) {
    // stage A (bf16 global, 16B loads, linear->swizzled)
#pragma unroll
    for (int p = 0; p < 4; ++p) {
      int row = arow + 32 * p;
      bf16x8 av = *reinterpret_cast<const bf16x8*>(A + (size_t)(m0 + row) * K + k0 + ac * 8);
      *reinterpret_cast<bf16x8*>(&As[swz(row, ac * 8)]) = av;
    }
    // stage W transposed + converted: Wt[n][k] bf16
#pragma unroll
    for (int p = 0; p < 8; ++p) {
      int kg = 4 * (bkh + 2 * p);
      const float* wp = W + (size_t)(k0 + kg) * N + n0 + bnn;
      bf16x4 wv = { f2bf(wp[0]), f2bf(wp[(size_t)N]), f2bf(wp[(size_t)2 * N]), f2bf(wp[(size_t)3 * N]) };
      *reinterpret_cast<bf16x4*>(&Bs[swz(bnn, kg)]) = wv;
    }
    __syncthreads();
#pragma unroll
    for (int kk = 0; kk < 64; kk += 32) {
      bf16x8 af[4], bfg[4];
#pragma unroll
      for (int mt = 0; mt < 4; ++mt)
        af[mt] = *reinterpret_cast<const bf16x8*>(&As[swz(wr * 64 + mt * 16 + r, kk + g * 8)]);
#pragma unroll
      for (int nt = 0; nt < 4; ++nt)
        bfg[nt] = *reinterpret_cast<const bf16x8*>(&Bs[swz(wc * 64 + nt * 16 + r, kk + g * 8)]);
#pragma unroll
      for (int mt = 0; mt < 4; ++mt)
#pragma unroll
        for (int nt = 0; nt < 4; ++nt)
          acc[mt][nt] = mfma16(af[mt], bfg[nt], acc[mt][nt]);
    }
    __syncthreads();
  }
  // epilogue; C mapping (HW-verified): col = n_tile + (lane&15), row = m_tile + 4*(lane>>4)+j
#pragma unroll
  for (int nt = 0; nt < 4; ++nt) {
    const int col = n0 + wc * 64 + nt * 16 + r;
    const float bv = (EPI == 3) ? 0.f : bias[col];
#pragma unroll
    for (int mt = 0; mt < 4; ++mt) {
#pragma unroll
      for (int j = 0; j < 4; ++j) {
        const int row = m0 + wr * 64 + mt * 16 + 4 * g + j;
        const size_t oi = (size_t)row * N + col;
        float vv = acc[mt][nt][j] + bv;
        if (EPI == 0) {
          ((short*)out)[oi] = f2bf(vv * scale);
        } else if (EPI == 1) {
          vv = 0.5f * vv * (1.f + erff(vv * 0.70710678118654752f));
          ((short*)out)[oi] = f2bf(vv);
        } else if (EPI == 2) {
          ((float*)out)[oi] = resid[oi] + vv;
        } else {
          ((float*)out)[oi] = vv;
        }
      }
    }
  }
}

// ---------- flash-style GQA attention ----------
// q: bf16 [2048][16*64] (already scaled by 1/8), k,v: bf16 [2048][4*64]
// o: bf16 [2048][16*64]. Non-causal, additive key mask.
__global__ __launch_bounds__(256) void attn_k(const short* __restrict__ q,
                                              const short* __restrict__ k,
                                              const short* __restrict__ v,
                                              const float* __restrict__ mask,
                                              short* __restrict__ o) {
  __shared__ short Ks[64 * 64];  // [s][d] swizzled
  __shared__ short Vt[64 * 64];  // [d][s] swizzled
  const int t = threadIdx.x, lane = t & 63, w = t >> 6;
  const int g = lane >> 4, r = lane & 15;
  const int h = blockIdx.y, qb = blockIdx.x, kvh = h >> 2;
  const int qrow = qb * 64 + w * 16 + r;

  const short* qp = q + (size_t)qrow * 1024 + h * 64;
  bf16x8 qf0 = *reinterpret_cast<const bf16x8*>(qp + g * 8);        // d = 8g..8g+7
  bf16x8 qf1 = *reinterpret_cast<const bf16x8*>(qp + 32 + g * 8);   // d = 32+8g..

  f32x4 oacc[4];
#pragma unroll
  for (int i = 0; i < 4; ++i) { f32x4 z = {0.f, 0.f, 0.f, 0.f}; oacc[i] = z; }
  float m_run = -INFINITY, l_run = 0.f;

  const int srow_ = t >> 3, c_ = t & 7;
  for (int s0 = 0; s0 < 2048; s0 += 64) {
    // stage K [s][d] and V transposed [d][s]
#pragma unroll
    for (int p = 0; p < 2; ++p) {
      int row = srow_ + 32 * p;
      bf16x8 kvv = *reinterpret_cast<const bf16x8*>(k + (size_t)(s0 + row) * 256 + kvh * 64 + c_ * 8);
      *reinterpret_cast<bf16x8*>(&Ks[swz(row, c_ * 8)]) = kvv;
      bf16x8 vvv = *reinterpret_cast<const bf16x8*>(v + (size_t)(s0 + row) * 256 + kvh * 64 + c_ * 8);
#pragma unroll
      for (int i = 0; i < 8; ++i) {
        int d = c_ * 8 + i;
        Vt[swz(d, row)] = vvv[i];
      }
    }
    __syncthreads();

    // S^T = K @ Q^T : lane holds S^T[s = st*16 + 4g + j][q = r]
    f32x4 sa[4];
#pragma unroll
    for (int st = 0; st < 4; ++st) {
      bf16x8 kf0 = *reinterpret_cast<const bf16x8*>(&Ks[swz(st * 16 + r, g * 8)]);
      bf16x8 kf1 = *reinterpret_cast<const bf16x8*>(&Ks[swz(st * 16 + r, 32 + g * 8)]);
      f32x4 z = {0.f, 0.f, 0.f, 0.f};
      z = mfma16(kf0, qf0, z);
      z = mfma16(kf1, qf1, z);
      sa[st] = z;
    }
    // online softmax (per q-row = per (r); reduce over g via shfl_xor 16,32)
    float sv[16];
    float pmax = -INFINITY;
#pragma unroll
    for (int st = 0; st < 4; ++st)
#pragma unroll
      for (int j = 0; j < 4; ++j) {
        float xx = sa[st][j] + mask[s0 + st * 16 + 4 * g + j];
        sv[st * 4 + j] = xx;
        pmax = fmaxf(pmax, xx);
      }
    pmax = fmaxf(pmax, __shfl_xor(pmax, 16));
    pmax = fmaxf(pmax, __shfl_xor(pmax, 32));
    float m_new = fmaxf(m_run, pmax);
    float corr = __expf(m_run - m_new);
    float psum = 0.f;
    short pb[16];
#pragma unroll
    for (int i = 0; i < 16; ++i) {
      float p = __expf(sv[i] - m_new);
      psum += p;
      pb[i] = f2bf(p);
    }
    psum += __shfl_xor(psum, 16);
    psum += __shfl_xor(psum, 32);
    l_run = l_run * corr + psum;
    m_run = m_new;
#pragma unroll
    for (int dt = 0; dt < 4; ++dt)
#pragma unroll
      for (int j = 0; j < 4; ++j) oacc[dt][j] *= corr;

    // O^T += V^T @ P^T, k-bijection s = 4g + (j&3) + 16*(j>>2) (+32*hs) on BOTH operands
#pragma unroll
    for (int hs = 0; hs < 2; ++hs) {
      bf16x8 pf = { pb[hs * 8 + 0], pb[hs * 8 + 1], pb[hs * 8 + 2], pb[hs * 8 + 3],
                    pb[hs * 8 + 4], pb[hs * 8 + 5], pb[hs * 8 + 6], pb[hs * 8 + 7] };
#pragma unroll
      for (int dt = 0; dt < 4; ++dt) {
        int d = dt * 16 + r;
        int c1 = 4 * g + 32 * hs;
        bf16x4 va  = *reinterpret_cast<const bf16x4*>(&Vt[swz(d, c1)]);
        bf16x4 vb2 = *reinterpret_cast<const bf16x4*>(&Vt[swz(d, c1 + 16)]);
        bf16x8 vf = { va[0], va[1], va[2], va[3], vb2[0], vb2[1], vb2[2], vb2[3] };
        oacc[dt] = mfma16(vf, pf, oacc[dt]);
      }
    }
    __syncthreads();
  }
  float inv = 1.f / l_run;
#pragma unroll
  for (int dt = 0; dt < 4; ++dt)
#pragma unroll
    for (int j = 0; j < 4; ++j) {
      int d = dt * 16 + 4 * g + j;
      o[(size_t)qrow * 1024 + h * 64 + d] = f2bf(oacc[dt][j] * inv);
    }
}

// ---------- launch ----------
extern "C" void kernel_launch(void* const* d_in, const int* in_sizes, int n_in,
                              void* d_out, int out_size, void* d_ws, size_t ws_size,
                              hipStream_t stream) {
  const int*   ids   = (const int*)d_in[0];
  const float* mask  = (const float*)d_in[1];
  const float* tok   = (const float*)d_in[2];
  const float* pos   = (const float*)d_in[3];
  const float* qW    = (const float*)d_in[4];
  const float* qbias = (const float*)d_in[5];
  const float* kW    = (const float*)d_in[6];
  const float* kbias = (const float*)d_in[7];
  const float* vW    = (const float*)d_in[8];
  const float* vbias = (const float*)d_in[9];
  const float* oW    = (const float*)d_in[10];
  const float* obias = (const float*)d_in[11];
  const float* m1W   = (const float*)d_in[12];
  const float* m1b   = (const float*)d_in[13];
  const float* m2W   = (const float*)d_in[14];
  const float* m2b   = (const float*)d_in[15];
  const float* ln1g  = (const float*)d_in[16];
  const float* ln1b  = (const float*)d_in[17];
  const float* ln2g  = (const float*)d_in[18];
  const float* ln2b  = (const float*)d_in[19];
  const float* lnfg  = (const float*)d_in[20];
  const float* lnfb  = (const float*)d_in[21];
  const float* headW = (const float*)d_in[22];
  float* out = (float*)d_out;

  char* ws = (char*)d_ws;
  float* x   = (float*)ws;                       // 8 MB f32 residual stream
  short* xb  = (short*)(ws + (8u << 20));        // 4 MB bf16 LN out
  short* qbf = (short*)(ws + (12u << 20));       // 4 MB
  short* kbf = (short*)(ws + (16u << 20));       // 1 MB
  short* vbf = (short*)(ws + (17u << 20));       // 1 MB
  short* ao  = (short*)(ws + (18u << 20));       // 4 MB
  short* ff  = (short*)(ws + (22u << 20));       // 16 MB bf16 [2048][4096]

  embed_k<<<2048, 256, 0, stream>>>(ids, tok, pos, x);

  for (int l = 0; l < 4; ++l) {
    ln_k<<<2048, 256, 0, stream>>>(x, ln1g + l * 1024, ln1b + l * 1024, xb);
    gemm_k<0><<<dim3(8, 16), 256, 0, stream>>>(xb, qW + (size_t)l * 1024 * 1024,
        qbias + l * 1024, nullptr, qbf, 2048, 1024, 1024, 0.125f);
    gemm_k<0><<<dim3(2, 16), 256, 0, stream>>>(xb, kW + (size_t)l * 1024 * 256,
        kbias + l * 256, nullptr, kbf, 2048, 256, 1024, 1.f);
    gemm_k<0><<<dim3(2, 16), 256, 0, stream>>>(xb, vW + (size_t)l * 1024 * 256,
        vbias + l * 256, nullptr, vbf, 2048, 256, 1024, 1.f);
    attn_k<<<dim3(32, 16), 256, 0, stream>>>(qbf, kbf, vbf, mask, ao);
    gemm_k<2><<<dim3(8, 16), 256, 0, stream>>>(ao, oW + (size_t)l * 1024 * 1024,
        obias + l * 1024, x, x, 2048, 1024, 1024, 1.f);
    ln_k<<<2048, 256, 0, stream>>>(x, ln2g + l * 1024, ln2b + l * 1024, xb);
    gemm_k<1><<<dim3(32, 16), 256, 0, stream>>>(xb, m1W + (size_t)l * 1024 * 4096,
        m1b + l * 4096, nullptr, ff, 2048, 4096, 1024, 1.f);
    gemm_k<2><<<dim3(8, 16), 256, 0, stream>>>(ff, m2W + (size_t)l * 4096 * 1024,
        m2b + l * 1024, x, x, 2048, 1024, 4096, 1.f);
  }
  ln_k<<<2048, 256, 0, stream>>>(x, lnfg, lnfb, xb);
  gemm_k<3><<<dim3(250, 16), 256, 0, stream>>>(xb, headW, nullptr, nullptr, out,
      2048, 32000, 1024, 1.f);
}

// Round 2
// 1363.273 us; speedup vs baseline: 3.1133x; 3.1133x over previous
//
#include <hip/hip_runtime.h>
#include <stdint.h>
#include <math.h>

// ---------- types ----------
typedef __attribute__((ext_vector_type(8))) short bf16x8;   // 8 bf16 (4 VGPR)
typedef __attribute__((ext_vector_type(4))) short bf16x4;
typedef __attribute__((ext_vector_type(4))) float f32x4;

__device__ __forceinline__ short f2bf(float f) {
  unsigned u = __builtin_bit_cast(unsigned, f);
  unsigned r = u + 0x7fffu + ((u >> 16) & 1u);
  return (short)(r >> 16);
}

__device__ __forceinline__ f32x4 mfma16(bf16x8 a, bf16x8 b, f32x4 c) {
  return __builtin_amdgcn_mfma_f32_16x16x32_bf16(a, b, c, 0, 0, 0);
}

// async global->LDS, 16B per lane. LDS dest = wave-uniform base + lane*16.
__device__ __forceinline__ void gload16(const void* g, void* l) {
  __builtin_amdgcn_global_load_lds((const __attribute__((address_space(1))) void*)g,
                                   (__attribute__((address_space(3))) void*)l, 16, 0, 0);
}

// LDS tile index: row-major [rows][64] bf16, 16B-chunk XOR swizzle on row&7.
__device__ __forceinline__ int swz(int row, int col) {
  return row * 64 + (((col >> 3) ^ (row & 7)) << 3) + (col & 7);
}

// ---------- embedding ----------
__global__ __launch_bounds__(256) void embed_k(const int* __restrict__ ids,
                                               const float* __restrict__ tok,
                                               const float* __restrict__ pos,
                                               float* __restrict__ x) {
  int row = blockIdx.x, t = threadIdx.x;
  int id = ids[row];
  const float4 a = *reinterpret_cast<const float4*>(tok + (size_t)id * 1024 + t * 4);
  const float4 b = *reinterpret_cast<const float4*>(pos + (size_t)row * 1024 + t * 4);
  float4 o = make_float4(a.x + b.x, a.y + b.y, a.z + b.z, a.w + b.w);
  *reinterpret_cast<float4*>(x + (size_t)row * 1024 + t * 4) = o;
}

// ---------- layernorm (f32 in, bf16 out) ----------
__global__ __launch_bounds__(256) void ln_k(const float* __restrict__ x,
                                            const float* __restrict__ gw,
                                            const float* __restrict__ bw,
                                            short* __restrict__ out) {
  int row = blockIdx.x, t = threadIdx.x;
  const float4 v = *reinterpret_cast<const float4*>(x + (size_t)row * 1024 + t * 4);
  float s = v.x + v.y + v.z + v.w;
  float q = v.x * v.x + v.y * v.y + v.z * v.z + v.w * v.w;
#pragma unroll
  for (int o = 32; o > 0; o >>= 1) { s += __shfl_xor(s, o); q += __shfl_xor(q, o); }
  __shared__ float sh[8];
  int w = t >> 6;
  if ((t & 63) == 0) { sh[w] = s; sh[4 + w] = q; }
  __syncthreads();
  float ts = sh[0] + sh[1] + sh[2] + sh[3];
  float tq = sh[4] + sh[5] + sh[6] + sh[7];
  float mean = ts * (1.f / 1024.f);
  float var  = tq * (1.f / 1024.f) - mean * mean;
  float rstd = rsqrtf(var + 1e-5f);
  const float4 gv = *reinterpret_cast<const float4*>(gw + t * 4);
  const float4 bv = *reinterpret_cast<const float4*>(bw + t * 4);
  bf16x4 ov = { f2bf((v.x - mean) * rstd * gv.x + bv.x),
                f2bf((v.y - mean) * rstd * gv.y + bv.y),
                f2bf((v.z - mean) * rstd * gv.z + bv.z),
                f2bf((v.w - mean) * rstd * gv.w + bv.w) };
  *reinterpret_cast<bf16x4*>(out + (size_t)row * 1024 + t * 4) = ov;
}

// ---------- weight transpose + f32->bf16 convert ----------
// W f32 [K,N] (layer z) -> Wt bf16 [rowOff+N rows][ldOut>=K], Wt[n][k] = W[k][n]*scale
__global__ __launch_bounds__(256) void tcvt_k(const float* __restrict__ W,
                                              short* __restrict__ Wt,
                                              int N, size_t inStride, size_t outStride,
                                              int rowOff, int ldOut, float scale) {
  __shared__ float T[64][65];
  const float* Win = W + blockIdx.z * inStride;
  short* Wout = Wt + blockIdx.z * outStride;
  const int n0 = blockIdx.x * 64, k0 = blockIdx.y * 64;
  const int t = threadIdx.x;
  const int nc = (t & 15) * 4, kr = t >> 4;
#pragma unroll
  for (int p = 0; p < 4; ++p) {
    const float4 v = *reinterpret_cast<const float4*>(Win + (size_t)(k0 + kr + 16 * p) * N + n0 + nc);
    T[kr + 16 * p][nc + 0] = v.x;
    T[kr + 16 * p][nc + 1] = v.y;
    T[kr + 16 * p][nc + 2] = v.z;
    T[kr + 16 * p][nc + 3] = v.w;
  }
  __syncthreads();
  const int n = t >> 2, ks = (t & 3) * 16;
  short tmp[16];
#pragma unroll
  for (int i = 0; i < 16; ++i) tmp[i] = f2bf(T[ks + i][n] * scale);
  short* op = Wout + (size_t)(rowOff + n0 + n) * ldOut + k0 + ks;
  *reinterpret_cast<bf16x8*>(op) = *reinterpret_cast<bf16x8*>(tmp);
  *reinterpret_cast<bf16x8*>(op + 8) = *reinterpret_cast<bf16x8*>(tmp + 8);
}

// concat qkv bias (q scaled by 0.125)
__global__ __launch_bounds__(256) void bqkv_k(const float* __restrict__ qb,
                                              const float* __restrict__ kb,
                                              const float* __restrict__ vb,
                                              float* __restrict__ o) {
  int l = blockIdx.y;
  int c = blockIdx.x * 256 + threadIdx.x;
  float v;
  if (c < 1024) v = qb[l * 1024 + c] * 0.125f;
  else if (c < 1280) v = kb[l * 256 + c - 1024];
  else v = vb[l * 256 + c - 1280];
  o[l * 1536 + c] = v;
}

// ---------- GEMM (m97 structure): C[M,N] = A_bf16[M,K] @ Wt_bf16[N,K]^T ----------
// EPI: 0 bf16 out (acc+bias); 1 bf16 out GELU(acc+bias); 2 f32 out resid+acc+bias; 3 f32 out acc
template <int EPI, bool XSWZ>
__global__ __launch_bounds__(256)
void gemm_bt(const short* __restrict__ A, const short* __restrict__ Wt,
             const float* __restrict__ bias, const float* __restrict__ resid,
             void* __restrict__ out, int M, int N, int K) {
  __shared__ short As[128 * 64];
  __shared__ short Bs[128 * 64];
  const int t = threadIdx.x;
  const int lane = t & 63, w = t >> 6;
  const int g = lane >> 4, r = lane & 15;
  const int wr = w >> 1, wc = w & 1;

  int bx = blockIdx.x, by = blockIdx.y;
  if (XSWZ) {
    const int nbx = gridDim.x, nwg = nbx * gridDim.y;
    const int bid = by * nbx + bx;
    const int q = nwg >> 3, rr = nwg & 7;
    const int xcd = bid & 7, loc = bid >> 3;
    const int sw = (xcd < rr ? xcd * (q + 1) : rr * (q + 1) + (xcd - rr) * q) + loc;
    bx = sw % nbx; by = sw / nbx;
  }
  const int m0 = by * 128, n0 = bx * 128;

  f32x4 acc[4][4];
#pragma unroll
  for (int i = 0; i < 4; ++i)
#pragma unroll
    for (int j = 0; j < 4; ++j) { f32x4 z = {0.f, 0.f, 0.f, 0.f}; acc[i][j] = z; }

  const int srow = lane >> 3, sslot = lane & 7;  // staging: 8 rows x 8 chunk-slots per issue

  for (int k0 = 0; k0 < K; k0 += 64) {
#pragma unroll
    for (int i = 0; i < 4; ++i) {
      const int rowA = w * 32 + i * 8 + srow;
      const int colA = (sslot ^ (srow & 7)) << 3;  // inverse-swizzled global source
      gload16(A + (size_t)(m0 + rowA) * K + k0 + colA, &As[(w * 32 + i * 8) * 64]);
    }
#pragma unroll
    for (int i = 0; i < 4; ++i) {
      const int rowB = w * 32 + i * 8 + srow;
      const int colB = (sslot ^ (srow & 7)) << 3;
      gload16(Wt + (size_t)(n0 + rowB) * K + k0 + colB, &Bs[(w * 32 + i * 8) * 64]);
    }
    __syncthreads();
#pragma unroll
    for (int kk = 0; kk < 64; kk += 32) {
      bf16x8 af[4], bfg[4];
#pragma unroll
      for (int mt = 0; mt < 4; ++mt)
        af[mt] = *reinterpret_cast<const bf16x8*>(&As[swz(wr * 64 + mt * 16 + r, kk + g * 8)]);
#pragma unroll
      for (int nt = 0; nt < 4; ++nt)
        bfg[nt] = *reinterpret_cast<const bf16x8*>(&Bs[swz(wc * 64 + nt * 16 + r, kk + g * 8)]);
#pragma unroll
      for (int mt = 0; mt < 4; ++mt)
#pragma unroll
        for (int nt = 0; nt < 4; ++nt)
          acc[mt][nt] = mfma16(af[mt], bfg[nt], acc[mt][nt]);
    }
    __syncthreads();
  }
  // epilogue; C mapping: col = n0 + wc*64 + nt*16 + r, row = m0 + wr*64 + mt*16 + 4g + j
#pragma unroll
  for (int nt = 0; nt < 4; ++nt) {
    const int col = n0 + wc * 64 + nt * 16 + r;
    const float bv = (EPI == 3) ? 0.f : bias[col];
#pragma unroll
    for (int mt = 0; mt < 4; ++mt) {
#pragma unroll
      for (int j = 0; j < 4; ++j) {
        const int row = m0 + wr * 64 + mt * 16 + 4 * g + j;
        const size_t oi = (size_t)row * N + col;
        float vv = acc[mt][nt][j] + bv;
        if (EPI == 0) {
          ((short*)out)[oi] = f2bf(vv);
        } else if (EPI == 1) {
          vv = 0.5f * vv * (1.f + erff(vv * 0.70710678118654752f));
          ((short*)out)[oi] = f2bf(vv);
        } else if (EPI == 2) {
          ((float*)out)[oi] = resid[oi] + vv;
        } else {
          ((float*)out)[oi] = vv;
        }
      }
    }
  }
}

// ---------- legacy GEMM (f32 weights) — fallback if ws too small ----------
template <int EPI>
__global__ __launch_bounds__(256)
void gemm_k(const short* __restrict__ A, const float* __restrict__ W,
            const float* __restrict__ bias, const float* resid, void* out,
            int M, int N, int K, float scale) {
  __shared__ short As[128 * 64];
  __shared__ short Bs[128 * 64];
  const int t = threadIdx.x;
  const int lane = t & 63;
  const int g = lane >> 4, r = lane & 15;
  const int wid = t >> 6, wr = wid >> 1, wc = wid & 1;
  const int m0 = blockIdx.y * 128, n0 = blockIdx.x * 128;
  f32x4 acc[4][4];
#pragma unroll
  for (int i = 0; i < 4; ++i)
#pragma unroll
    for (int j = 0; j < 4; ++j) { f32x4 z = {0.f, 0.f, 0.f, 0.f}; acc[i][j] = z; }
  const int arow = t >> 3, ac = t & 7;
  const int bnn = t >> 1, bkh = t & 1;
  for (int k0 = 0; k0 < K; k0 += 64) {
#pragma unroll
    for (int p = 0; p < 4; ++p) {
      int row = arow + 32 * p;
      bf16x8 av = *reinterpret_cast<const bf16x8*>(A + (size_t)(m0 + row) * K + k0 + ac * 8);
      *reinterpret_cast<bf16x8*>(&As[swz(row, ac * 8)]) = av;
    }
#pragma unroll
    for (int p = 0; p < 8; ++p) {
      int kg = 4 * (bkh + 2 * p);
      const float* wp = W + (size_t)(k0 + kg) * N + n0 + bnn;
      bf16x4 wv = { f2bf(wp[0]), f2bf(wp[(size_t)N]), f2bf(wp[(size_t)2 * N]), f2bf(wp[(size_t)3 * N]) };
      *reinterpret_cast<bf16x4*>(&Bs[swz(bnn, kg)]) = wv;
    }
    __syncthreads();
#pragma unroll
    for (int kk = 0; kk < 64; kk += 32) {
      bf16x8 af[4], bfg[4];
#pragma unroll
      for (int mt = 0; mt < 4; ++mt)
        af[mt] = *reinterpret_cast<const bf16x8*>(&As[swz(wr * 64 + mt * 16 + r, kk + g * 8)]);
#pragma unroll
      for (int nt = 0; nt < 4; ++nt)
        bfg[nt] = *reinterpret_cast<const bf16x8*>(&Bs[swz(wc * 64 + nt * 16 + r, kk + g * 8)]);
#pragma unroll
      for (int mt = 0; mt < 4; ++mt)
#pragma unroll
        for (int nt = 0; nt < 4; ++nt)
          acc[mt][nt] = mfma16(af[mt], bfg[nt], acc[mt][nt]);
    }
    __syncthreads();
  }
#pragma unroll
  for (int nt = 0; nt < 4; ++nt) {
    const int col = n0 + wc * 64 + nt * 16 + r;
    const float bv = (EPI == 3) ? 0.f : bias[col];
#pragma unroll
    for (int mt = 0; mt < 4; ++mt) {
#pragma unroll
      for (int j = 0; j < 4; ++j) {
        const int row = m0 + wr * 64 + mt * 16 + 4 * g + j;
        const size_t oi = (size_t)row * N + col;
        float vv = acc[mt][nt][j] + bv;
        if (EPI == 0) {
          ((short*)out)[oi] = f2bf(vv * scale);
        } else if (EPI == 1) {
          vv = 0.5f * vv * (1.f + erff(vv * 0.70710678118654752f));
          ((short*)out)[oi] = f2bf(vv);
        } else if (EPI == 2) {
          ((float*)out)[oi] = resid[oi] + vv;
        } else {
          ((float*)out)[oi] = vv;
        }
      }
    }
  }
}

// ---------- flash-style GQA attention ----------
// q/k/v are pointers into row-major bf16 activations with leading dims qld/kvld.
// q pre-scaled by 1/8 (folded into weights). o: bf16 [2048][1024]. Additive key mask.
__global__ __launch_bounds__(256) void attn_k(const short* __restrict__ q, int qld,
                                              const short* __restrict__ k,
                                              const short* __restrict__ v, int kvld,
                                              const float* __restrict__ mask,
                                              short* __restrict__ o) {
  __shared__ short Ks[64 * 64];  // [s][d] swizzled
  __shared__ short Vt[64 * 64];  // [d][s] swizzled
  const int t = threadIdx.x, lane = t & 63, w = t >> 6;
  const int g = lane >> 4, r = lane & 15;
  const int h = blockIdx.y, qb = blockIdx.x, kvh = h >> 2;
  const int qrow = qb * 64 + w * 16 + r;

  const short* qp = q + (size_t)qrow * qld + h * 64;
  bf16x8 qf0 = *reinterpret_cast<const bf16x8*>(qp + g * 8);
  bf16x8 qf1 = *reinterpret_cast<const bf16x8*>(qp + 32 + g * 8);

  f32x4 oacc[4];
#pragma unroll
  for (int i = 0; i < 4; ++i) { f32x4 z = {0.f, 0.f, 0.f, 0.f}; oacc[i] = z; }
  float m_run = -INFINITY, l_run = 0.f;

  const int srow_ = t >> 3, c_ = t & 7;
  for (int s0 = 0; s0 < 2048; s0 += 64) {
#pragma unroll
    for (int p = 0; p < 2; ++p) {
      int row = srow_ + 32 * p;
      bf16x8 kvv = *reinterpret_cast<const bf16x8*>(k + (size_t)(s0 + row) * kvld + kvh * 64 + c_ * 8);
      *reinterpret_cast<bf16x8*>(&Ks[swz(row, c_ * 8)]) = kvv;
      bf16x8 vvv = *reinterpret_cast<const bf16x8*>(v + (size_t)(s0 + row) * kvld + kvh * 64 + c_ * 8);
#pragma unroll
      for (int i = 0; i < 8; ++i) {
        int d = c_ * 8 + i;
        Vt[swz(d, row)] = vvv[i];
      }
    }
    __syncthreads();

    f32x4 sa[4];
#pragma unroll
    for (int st = 0; st < 4; ++st) {
      bf16x8 kf0 = *reinterpret_cast<const bf16x8*>(&Ks[swz(st * 16 + r, g * 8)]);
      bf16x8 kf1 = *reinterpret_cast<const bf16x8*>(&Ks[swz(st * 16 + r, 32 + g * 8)]);
      f32x4 z = {0.f, 0.f, 0.f, 0.f};
      z = mfma16(kf0, qf0, z);
      z = mfma16(kf1, qf1, z);
      sa[st] = z;
    }
    float sv[16];
    float pmax = -INFINITY;
#pragma unroll
    for (int st = 0; st < 4; ++st)
#pragma unroll
      for (int j = 0; j < 4; ++j) {
        float xx = sa[st][j] + mask[s0 + st * 16 + 4 * g + j];
        sv[st * 4 + j] = xx;
        pmax = fmaxf(pmax, xx);
      }
    pmax = fmaxf(pmax, __shfl_xor(pmax, 16));
    pmax = fmaxf(pmax, __shfl_xor(pmax, 32));
    float m_new = fmaxf(m_run, pmax);
    float corr = __expf(m_run - m_new);
    float psum = 0.f;
    short pb[16];
#pragma unroll
    for (int i = 0; i < 16; ++i) {
      float p = __expf(sv[i] - m_new);
      psum += p;
      pb[i] = f2bf(p);
    }
    psum += __shfl_xor(psum, 16);
    psum += __shfl_xor(psum, 32);
    l_run = l_run * corr + psum;
    m_run = m_new;
#pragma unroll
    for (int dt = 0; dt < 4; ++dt)
#pragma unroll
      for (int j = 0; j < 4; ++j) oacc[dt][j] *= corr;

#pragma unroll
    for (int hs = 0; hs < 2; ++hs) {
      bf16x8 pf = { pb[hs * 8 + 0], pb[hs * 8 + 1], pb[hs * 8 + 2], pb[hs * 8 + 3],
                    pb[hs * 8 + 4], pb[hs * 8 + 5], pb[hs * 8 + 6], pb[hs * 8 + 7] };
#pragma unroll
      for (int dt = 0; dt < 4; ++dt) {
        int d = dt * 16 + r;
        int c1 = 4 * g + 32 * hs;
        bf16x4 va  = *reinterpret_cast<const bf16x4*>(&Vt[swz(d, c1)]);
        bf16x4 vb2 = *reinterpret_cast<const bf16x4*>(&Vt[swz(d, c1 + 16)]);
        bf16x8 vf = { va[0], va[1], va[2], va[3], vb2[0], vb2[1], vb2[2], vb2[3] };
        oacc[dt] = mfma16(vf, pf, oacc[dt]);
      }
    }
    __syncthreads();
  }
  float inv = 1.f / l_run;
#pragma unroll
  for (int dt = 0; dt < 4; ++dt)
#pragma unroll
    for (int j = 0; j < 4; ++j) {
      int d = dt * 16 + 4 * g + j;
      o[(size_t)qrow * 1024 + h * 64 + d] = f2bf(oacc[dt][j] * inv);
    }
}

// ---------- launch ----------
extern "C" void kernel_launch(void* const* d_in, const int* in_sizes, int n_in,
                              void* d_out, int out_size, void* d_ws, size_t ws_size,
                              hipStream_t stream) {
  const int*   ids   = (const int*)d_in[0];
  const float* mask  = (const float*)d_in[1];
  const float* tok   = (const float*)d_in[2];
  const float* pos   = (const float*)d_in[3];
  const float* qW    = (const float*)d_in[4];
  const float* qbias = (const float*)d_in[5];
  const float* kW    = (const float*)d_in[6];
  const float* kbias = (const float*)d_in[7];
  const float* vW    = (const float*)d_in[8];
  const float* vbias = (const float*)d_in[9];
  const float* oW    = (const float*)d_in[10];
  const float* obias = (const float*)d_in[11];
  const float* m1W   = (const float*)d_in[12];
  const float* m1b   = (const float*)d_in[13];
  const float* m2W   = (const float*)d_in[14];
  const float* m2b   = (const float*)d_in[15];
  const float* ln1g  = (const float*)d_in[16];
  const float* ln1b  = (const float*)d_in[17];
  const float* ln2g  = (const float*)d_in[18];
  const float* ln2b  = (const float*)d_in[19];
  const float* lnfg  = (const float*)d_in[20];
  const float* lnfb  = (const float*)d_in[21];
  const float* headW = (const float*)d_in[22];
  float* out = (float*)d_out;

  char* ws = (char*)d_ws;
  // activation buffers (shared by both paths)
  float* x   = (float*)ws;                        // 8 MB
  short* xb  = (short*)(ws + 8388608ull);         // 4 MB

  const size_t OFF_QKV  = 12582912ull;   // 6 MB  bf16 [2048][1536]
  const size_t OFF_AO   = 18874368ull;   // 4 MB
  const size_t OFF_FF   = 23068672ull;   // 16 MB
  const size_t OFF_BQ   = 39845888ull;   // 24 KB f32 [4][1536]
  const size_t OFF_WQKV = 39870464ull;   // 12 MB bf16 [4][1536][1024]
  const size_t OFF_WO   = 52453376ull;   // 8 MB  bf16 [4][1024][1024]
  const size_t OFF_WM1  = 60841984ull;   // 32 MB bf16 [4][4096][1024]
  const size_t OFF_WM2  = 94396416ull;   // 32 MB bf16 [4][1024][4096]
  const size_t OFF_WH   = 127950848ull;  // 64 MB bf16 [32000][1024]
  const size_t NEED     = 193486848ull;

  if (ws_size >= NEED) {
    short* qkv  = (short*)(ws + OFF_QKV);
    short* ao   = (short*)(ws + OFF_AO);
    short* ff   = (short*)(ws + OFF_FF);
    float* bqv  = (float*)(ws + OFF_BQ);
    short* Wqkv = (short*)(ws + OFF_WQKV);
    short* Wo   = (short*)(ws + OFF_WO);
    short* Wm1  = (short*)(ws + OFF_WM1);
    short* Wm2  = (short*)(ws + OFF_WM2);
    short* Wh   = (short*)(ws + OFF_WH);

    // weight conversion (per call; ~465 MB traffic)
    tcvt_k<<<dim3(16, 16, 4), 256, 0, stream>>>(qW, Wqkv, 1024, 1048576ull, 1572864ull, 0, 1024, 0.125f);
    tcvt_k<<<dim3(4, 16, 4),  256, 0, stream>>>(kW, Wqkv, 256,  262144ull,  1572864ull, 1024, 1024, 1.f);
    tcvt_k<<<dim3(4, 16, 4),  256, 0, stream>>>(vW, Wqkv, 256,  262144ull,  1572864ull, 1280, 1024, 1.f);
    tcvt_k<<<dim3(16, 16, 4), 256, 0, stream>>>(oW, Wo, 1024, 1048576ull, 1048576ull, 0, 1024, 1.f);
    tcvt_k<<<dim3(64, 16, 4), 256, 0, stream>>>(m1W, Wm1, 4096, 4194304ull, 4194304ull, 0, 1024, 1.f);
    tcvt_k<<<dim3(16, 64, 4), 256, 0, stream>>>(m2W, Wm2, 1024, 4194304ull, 4194304ull, 0, 4096, 1.f);
    tcvt_k<<<dim3(500, 16, 1), 256, 0, stream>>>(headW, Wh, 32000, 0ull, 0ull, 0, 1024, 1.f);
    bqkv_k<<<dim3(6, 4), 256, 0, stream>>>(qbias, kbias, vbias, bqv);

    embed_k<<<2048, 256, 0, stream>>>(ids, tok, pos, x);

    for (int l = 0; l < 4; ++l) {
      short* Wq_l  = Wqkv + (size_t)l * 1536 * 1024;
      short* Wo_l  = Wo   + (size_t)l * 1024 * 1024;
      short* Wm1_l = Wm1  + (size_t)l * 4096 * 1024;
      short* Wm2_l = Wm2  + (size_t)l * 1024 * 4096;

      ln_k<<<2048, 256, 0, stream>>>(x, ln1g + l * 1024, ln1b + l * 1024, xb);
      gemm_bt<0, false><<<dim3(12, 16), 256, 0, stream>>>(xb, Wq_l, bqv + l * 1536, nullptr,
                                                          qkv, 2048, 1536, 1024);
      attn_k<<<dim3(32, 16), 256, 0, stream>>>(qkv, 1536, qkv + 1024, qkv + 1280, 1536, mask, ao);
      gemm_bt<2, false><<<dim3(8, 16), 256, 0, stream>>>(ao, Wo_l, obias + l * 1024, x,
                                                         x, 2048, 1024, 1024);
      ln_k<<<2048, 256, 0, stream>>>(x, ln2g + l * 1024, ln2b + l * 1024, xb);
      gemm_bt<1, false><<<dim3(32, 16), 256, 0, stream>>>(xb, Wm1_l, m1b + l * 4096, nullptr,
                                                          ff, 2048, 4096, 1024);
      gemm_bt<2, false><<<dim3(8, 16), 256, 0, stream>>>(ff, Wm2_l, m2b + l * 1024, x,
                                                         x, 2048, 1024, 4096);
    }
    ln_k<<<2048, 256, 0, stream>>>(x, lnfg, lnfb, xb);
    gemm_bt<3, true><<<dim3(250, 16), 256, 0, stream>>>(xb, Wh, nullptr, nullptr,
                                                        out, 2048, 32000, 1024);
  } else {
    // fallback: round-1 path (f32 weights in GEMM), needs < 39 MB ws
    short* qbf = (short*)(ws + (12u << 20));
    short* kbf = (short*)(ws + (16u << 20));
    short* vbf = (short*)(ws + (17u << 20));
    short* ao  = (short*)(ws + (18u << 20));
    short* ff  = (short*)(ws + (22u << 20));

    embed_k<<<2048, 256, 0, stream>>>(ids, tok, pos, x);
    for (int l = 0; l < 4; ++l) {
      ln_k<<<2048, 256, 0, stream>>>(x, ln1g + l * 1024, ln1b + l * 1024, xb);
      gemm_k<0><<<dim3(8, 16), 256, 0, stream>>>(xb, qW + (size_t)l * 1024 * 1024,
          qbias + l * 1024, nullptr, qbf, 2048, 1024, 1024, 0.125f);
      gemm_k<0><<<dim3(2, 16), 256, 0, stream>>>(xb, kW + (size_t)l * 1024 * 256,
          kbias + l * 256, nullptr, kbf, 2048, 256, 1024, 1.f);
      gemm_k<0><<<dim3(2, 16), 256, 0, stream>>>(xb, vW + (size_t)l * 1024 * 256,
          vbias + l * 256, nullptr, vbf, 2048, 256, 1024, 1.f);
      attn_k<<<dim3(32, 16), 256, 0, stream>>>(qbf, 1024, kbf, vbf, 256, mask, ao);
      gemm_k<2><<<dim3(8, 16), 256, 0, stream>>>(ao, oW + (size_t)l * 1024 * 1024,
          obias + l * 1024, x, x, 2048, 1024, 1024, 1.f);
      ln_k<<<2048, 256, 0, stream>>>(x, ln2g + l * 1024, ln2b + l * 1024, xb);
      gemm_k<1><<<dim3(32, 16), 256, 0, stream>>>(xb, m1W + (size_t)l * 1024 * 4096,
          m1b + l * 4096, nullptr, ff, 2048, 4096, 1024, 1.f);
      gemm_k<2><<<dim3(8, 16), 256, 0, stream>>>(ff, m2W + (size_t)l * 4096 * 1024,
          m2b + l * 1024, x, x, 2048, 1024, 4096, 1.f);
    }
    ln_k<<<2048, 256, 0, stream>>>(x, lnfg, lnfb, xb);
    gemm_k<3><<<dim3(250, 16), 256, 0, stream>>>(xb, headW, nullptr, nullptr, out,
        2048, 32000, 1024, 1.f);
  }
}

// Round 3
// 1340.134 us; speedup vs baseline: 3.1670x; 1.0173x over previous
//
#include <hip/hip_runtime.h>
#include <stdint.h>
#include <math.h>

// ---------- types ----------
typedef __attribute__((ext_vector_type(8))) short bf16x8;   // 8 bf16 (4 VGPR)
typedef __attribute__((ext_vector_type(4))) short bf16x4;
typedef __attribute__((ext_vector_type(4))) float f32x4;

__device__ __forceinline__ short f2bf(float f) {
  unsigned u = __builtin_bit_cast(unsigned, f);
  unsigned r = u + 0x7fffu + ((u >> 16) & 1u);
  return (short)(r >> 16);
}

__device__ __forceinline__ f32x4 mfma16(bf16x8 a, bf16x8 b, f32x4 c) {
  return __builtin_amdgcn_mfma_f32_16x16x32_bf16(a, b, c, 0, 0, 0);
}

// async global->LDS, 16B per lane. LDS dest = wave-uniform base + lane*16.
__device__ __forceinline__ void gload16(const void* g, void* l) {
  __builtin_amdgcn_global_load_lds((const __attribute__((address_space(1))) void*)g,
                                   (__attribute__((address_space(3))) void*)l, 16, 0, 0);
}

// LDS tile index: row-major [rows][64] bf16, 16B-chunk XOR swizzle on row&7.
__device__ __forceinline__ int swz(int row, int col) {
  return row * 64 + (((col >> 3) ^ (row & 7)) << 3) + (col & 7);
}

// ---------- embedding ----------
__global__ __launch_bounds__(256) void embed_k(const int* __restrict__ ids,
                                               const float* __restrict__ tok,
                                               const float* __restrict__ pos,
                                               float* __restrict__ x) {
  int row = blockIdx.x, t = threadIdx.x;
  int id = ids[row];
  const float4 a = *reinterpret_cast<const float4*>(tok + (size_t)id * 1024 + t * 4);
  const float4 b = *reinterpret_cast<const float4*>(pos + (size_t)row * 1024 + t * 4);
  float4 o = make_float4(a.x + b.x, a.y + b.y, a.z + b.z, a.w + b.w);
  *reinterpret_cast<float4*>(x + (size_t)row * 1024 + t * 4) = o;
}

// ---------- layernorm (f32 in, bf16 out) ----------
__global__ __launch_bounds__(256) void ln_k(const float* __restrict__ x,
                                            const float* __restrict__ gw,
                                            const float* __restrict__ bw,
                                            short* __restrict__ out) {
  int row = blockIdx.x, t = threadIdx.x;
  const float4 v = *reinterpret_cast<const float4*>(x + (size_t)row * 1024 + t * 4);
  float s = v.x + v.y + v.z + v.w;
  float q = v.x * v.x + v.y * v.y + v.z * v.z + v.w * v.w;
#pragma unroll
  for (int o = 32; o > 0; o >>= 1) { s += __shfl_xor(s, o); q += __shfl_xor(q, o); }
  __shared__ float sh[8];
  int w = t >> 6;
  if ((t & 63) == 0) { sh[w] = s; sh[4 + w] = q; }
  __syncthreads();
  float ts = sh[0] + sh[1] + sh[2] + sh[3];
  float tq = sh[4] + sh[5] + sh[6] + sh[7];
  float mean = ts * (1.f / 1024.f);
  float var  = tq * (1.f / 1024.f) - mean * mean;
  float rstd = rsqrtf(var + 1e-5f);
  const float4 gv = *reinterpret_cast<const float4*>(gw + t * 4);
  const float4 bv = *reinterpret_cast<const float4*>(bw + t * 4);
  bf16x4 ov = { f2bf((v.x - mean) * rstd * gv.x + bv.x),
                f2bf((v.y - mean) * rstd * gv.y + bv.y),
                f2bf((v.z - mean) * rstd * gv.z + bv.z),
                f2bf((v.w - mean) * rstd * gv.w + bv.w) };
  *reinterpret_cast<bf16x4*>(out + (size_t)row * 1024 + t * 4) = ov;
}

// ---------- weight transpose + f32->bf16 convert ----------
__global__ __launch_bounds__(256) void tcvt_k(const float* __restrict__ W,
                                              short* __restrict__ Wt,
                                              int N, size_t inStride, size_t outStride,
                                              int rowOff, int ldOut, float scale) {
  __shared__ float T[64][65];
  const float* Win = W + blockIdx.z * inStride;
  short* Wout = Wt + blockIdx.z * outStride;
  const int n0 = blockIdx.x * 64, k0 = blockIdx.y * 64;
  const int t = threadIdx.x;
  const int nc = (t & 15) * 4, kr = t >> 4;
#pragma unroll
  for (int p = 0; p < 4; ++p) {
    const float4 v = *reinterpret_cast<const float4*>(Win + (size_t)(k0 + kr + 16 * p) * N + n0 + nc);
    T[kr + 16 * p][nc + 0] = v.x;
    T[kr + 16 * p][nc + 1] = v.y;
    T[kr + 16 * p][nc + 2] = v.z;
    T[kr + 16 * p][nc + 3] = v.w;
  }
  __syncthreads();
  const int n = t >> 2, ks = (t & 3) * 16;
  short tmp[16];
#pragma unroll
  for (int i = 0; i < 16; ++i) tmp[i] = f2bf(T[ks + i][n] * scale);
  short* op = Wout + (size_t)(rowOff + n0 + n) * ldOut + k0 + ks;
  *reinterpret_cast<bf16x8*>(op) = *reinterpret_cast<bf16x8*>(tmp);
  *reinterpret_cast<bf16x8*>(op + 8) = *reinterpret_cast<bf16x8*>(tmp + 8);
}

// concat qkv bias (q scaled by 0.125)
__global__ __launch_bounds__(256) void bqkv_k(const float* __restrict__ qb,
                                              const float* __restrict__ kb,
                                              const float* __restrict__ vb,
                                              float* __restrict__ o) {
  int l = blockIdx.y;
  int c = blockIdx.x * 256 + threadIdx.x;
  float v;
  if (c < 1024) v = qb[l * 1024 + c] * 0.125f;
  else if (c < 1280) v = kb[l * 256 + c - 1024];
  else v = vb[l * 256 + c - 1280];
  o[l * 1536 + c] = v;
}

// ---------- V transpose: v[s][kvh*64+d] (ld vld) -> vt[kvh][d][s]  (bf16) ----------
__global__ __launch_bounds__(256) void vtr_k(const short* __restrict__ v, int vld,
                                             short* __restrict__ vt) {
  __shared__ short T[64][80];  // 160B row stride (16B multiple)
  const int kvh = blockIdx.y;
  const int s0 = blockIdx.x * 64;
  const int t = threadIdx.x;
  const int row = t >> 3, ch = t & 7;
#pragma unroll
  for (int p = 0; p < 2; ++p) {
    int s = row + 32 * p;
    bf16x8 vv = *reinterpret_cast<const bf16x8*>(v + (size_t)(s0 + s) * vld + kvh * 64 + ch * 8);
    *reinterpret_cast<bf16x8*>(&T[s][ch * 8]) = vv;
  }
  __syncthreads();
#pragma unroll
  for (int p = 0; p < 2; ++p) {
    int d = row + 32 * p;
    short tmp[8];
#pragma unroll
    for (int i = 0; i < 8; ++i) tmp[i] = T[ch * 8 + i][d];
    *reinterpret_cast<bf16x8*>(vt + (size_t)(kvh * 64 + d) * 2048 + s0 + ch * 8) =
        *reinterpret_cast<bf16x8*>(tmp);
  }
}

// ---------- GEMM (m97 structure): C[M,N] = A_bf16[M,K] @ Wt_bf16[N,K]^T ----------
// EPI: 0 bf16 out (acc+bias); 1 bf16 out GELU(acc+bias); 2 f32 out resid+acc+bias; 3 f32 out acc
// XSWZ: 0 = identity; 1 = m-fastest order + bijective XCD chunking (L2 W-panel reuse)
template <int EPI, int XSWZ>
__global__ __launch_bounds__(256)
void gemm_bt(const short* __restrict__ A, const short* __restrict__ Wt,
             const float* __restrict__ bias, const float* __restrict__ resid,
             void* __restrict__ out, int M, int N, int K) {
  __shared__ short As[128 * 64];
  __shared__ short Bs[128 * 64];
  const int t = threadIdx.x;
  const int lane = t & 63, w = t >> 6;
  const int g = lane >> 4, r = lane & 15;
  const int wr = w >> 1, wc = w & 1;

  int bx = blockIdx.x, by = blockIdx.y;
  if (XSWZ == 1) {
    const int nbx = gridDim.x, nby = gridDim.y, nwg = nbx * nby;
    const int bid = by * nbx + bx;
    const int q = nwg >> 3, rr = nwg & 7;
    const int xcd = bid & 7, loc = bid >> 3;
    const int sw = (xcd < rr ? xcd * (q + 1) : rr * (q + 1) + (xcd - rr) * q) + loc;
    by = sw % nby; bx = sw / nby;  // m-fastest: XCD-contiguous blocks share an n-panel
  }
  const int m0 = by * 128, n0 = bx * 128;

  f32x4 acc[4][4];
#pragma unroll
  for (int i = 0; i < 4; ++i)
#pragma unroll
    for (int j = 0; j < 4; ++j) { f32x4 z = {0.f, 0.f, 0.f, 0.f}; acc[i][j] = z; }

  const int srow = lane >> 3, sslot = lane & 7;

  for (int k0 = 0; k0 < K; k0 += 64) {
#pragma unroll
    for (int i = 0; i < 4; ++i) {
      const int rowA = w * 32 + i * 8 + srow;
      const int colA = (sslot ^ (srow & 7)) << 3;
      gload16(A + (size_t)(m0 + rowA) * K + k0 + colA, &As[(w * 32 + i * 8) * 64]);
    }
#pragma unroll
    for (int i = 0; i < 4; ++i) {
      const int rowB = w * 32 + i * 8 + srow;
      const int colB = (sslot ^ (srow & 7)) << 3;
      gload16(Wt + (size_t)(n0 + rowB) * K + k0 + colB, &Bs[(w * 32 + i * 8) * 64]);
    }
    __syncthreads();
#pragma unroll
    for (int kk = 0; kk < 64; kk += 32) {
      bf16x8 af[4], bfg[4];
#pragma unroll
      for (int mt = 0; mt < 4; ++mt)
        af[mt] = *reinterpret_cast<const bf16x8*>(&As[swz(wr * 64 + mt * 16 + r, kk + g * 8)]);
#pragma unroll
      for (int nt = 0; nt < 4; ++nt)
        bfg[nt] = *reinterpret_cast<const bf16x8*>(&Bs[swz(wc * 64 + nt * 16 + r, kk + g * 8)]);
#pragma unroll
      for (int mt = 0; mt < 4; ++mt)
#pragma unroll
        for (int nt = 0; nt < 4; ++nt)
          acc[mt][nt] = mfma16(af[mt], bfg[nt], acc[mt][nt]);
    }
    __syncthreads();
  }
#pragma unroll
  for (int nt = 0; nt < 4; ++nt) {
    const int col = n0 + wc * 64 + nt * 16 + r;
    const float bv = (EPI == 3) ? 0.f : bias[col];
#pragma unroll
    for (int mt = 0; mt < 4; ++mt) {
#pragma unroll
      for (int j = 0; j < 4; ++j) {
        const int row = m0 + wr * 64 + mt * 16 + 4 * g + j;
        const size_t oi = (size_t)row * N + col;
        float vv = acc[mt][nt][j] + bv;
        if (EPI == 0) {
          ((short*)out)[oi] = f2bf(vv);
        } else if (EPI == 1) {
          vv = 0.5f * vv * (1.f + erff(vv * 0.70710678118654752f));
          ((short*)out)[oi] = f2bf(vv);
        } else if (EPI == 2) {
          ((float*)out)[oi] = resid[oi] + vv;
        } else {
          ((float*)out)[oi] = vv;
        }
      }
    }
  }
}

// ---------- legacy GEMM (f32 weights) — fallback if ws too small ----------
template <int EPI>
__global__ __launch_bounds__(256)
void gemm_k(const short* __restrict__ A, const float* __restrict__ W,
            const float* __restrict__ bias, const float* resid, void* out,
            int M, int N, int K, float scale) {
  __shared__ short As[128 * 64];
  __shared__ short Bs[128 * 64];
  const int t = threadIdx.x;
  const int lane = t & 63;
  const int g = lane >> 4, r = lane & 15;
  const int wid = t >> 6, wr = wid >> 1, wc = wid & 1;
  const int m0 = blockIdx.y * 128, n0 = blockIdx.x * 128;
  f32x4 acc[4][4];
#pragma unroll
  for (int i = 0; i < 4; ++i)
#pragma unroll
    for (int j = 0; j < 4; ++j) { f32x4 z = {0.f, 0.f, 0.f, 0.f}; acc[i][j] = z; }
  const int arow = t >> 3, ac = t & 7;
  const int bnn = t >> 1, bkh = t & 1;
  for (int k0 = 0; k0 < K; k0 += 64) {
#pragma unroll
    for (int p = 0; p < 4; ++p) {
      int row = arow + 32 * p;
      bf16x8 av = *reinterpret_cast<const bf16x8*>(A + (size_t)(m0 + row) * K + k0 + ac * 8);
      *reinterpret_cast<bf16x8*>(&As[swz(row, ac * 8)]) = av;
    }
#pragma unroll
    for (int p = 0; p < 8; ++p) {
      int kg = 4 * (bkh + 2 * p);
      const float* wp = W + (size_t)(k0 + kg) * N + n0 + bnn;
      bf16x4 wv = { f2bf(wp[0]), f2bf(wp[(size_t)N]), f2bf(wp[(size_t)2 * N]), f2bf(wp[(size_t)3 * N]) };
      *reinterpret_cast<bf16x4*>(&Bs[swz(bnn, kg)]) = wv;
    }
    __syncthreads();
#pragma unroll
    for (int kk = 0; kk < 64; kk += 32) {
      bf16x8 af[4], bfg[4];
#pragma unroll
      for (int mt = 0; mt < 4; ++mt)
        af[mt] = *reinterpret_cast<const bf16x8*>(&As[swz(wr * 64 + mt * 16 + r, kk + g * 8)]);
#pragma unroll
      for (int nt = 0; nt < 4; ++nt)
        bfg[nt] = *reinterpret_cast<const bf16x8*>(&Bs[swz(wc * 64 + nt * 16 + r, kk + g * 8)]);
#pragma unroll
      for (int mt = 0; mt < 4; ++mt)
#pragma unroll
        for (int nt = 0; nt < 4; ++nt)
          acc[mt][nt] = mfma16(af[mt], bfg[nt], acc[mt][nt]);
    }
    __syncthreads();
  }
#pragma unroll
  for (int nt = 0; nt < 4; ++nt) {
    const int col = n0 + wc * 64 + nt * 16 + r;
    const float bv = (EPI == 3) ? 0.f : bias[col];
#pragma unroll
    for (int mt = 0; mt < 4; ++mt) {
#pragma unroll
      for (int j = 0; j < 4; ++j) {
        const int row = m0 + wr * 64 + mt * 16 + 4 * g + j;
        const size_t oi = (size_t)row * N + col;
        float vv = acc[mt][nt][j] + bv;
        if (EPI == 0) {
          ((short*)out)[oi] = f2bf(vv * scale);
        } else if (EPI == 1) {
          vv = 0.5f * vv * (1.f + erff(vv * 0.70710678118654752f));
          ((short*)out)[oi] = f2bf(vv);
        } else if (EPI == 2) {
          ((float*)out)[oi] = resid[oi] + vv;
        } else {
          ((float*)out)[oi] = vv;
        }
      }
    }
  }
}

// ---------- flash-style GQA attention (dbuf, gload_lds staging) ----------
// q rows: bf16 ld qld (pre-scaled). k rows: ld kld (col offset applied by caller).
// vt: [4][64][2048] bf16. o: bf16 [2048][1024]. Additive key mask.
__global__ __launch_bounds__(256) void attn_k(const short* __restrict__ q, int qld,
                                              const short* __restrict__ k, int kld,
                                              const short* __restrict__ vt,
                                              const float* __restrict__ mask,
                                              short* __restrict__ o) {
  __shared__ short Ks[2][64 * 64];  // [s][d], 16B-chunk swizzled
  __shared__ short Vs[2][64 * 64];  // [d][s], 16B-chunk swizzled
  const int t = threadIdx.x, lane = t & 63, w = t >> 6;
  const int g = lane >> 4, r = lane & 15;
  const int h = blockIdx.y, qb = blockIdx.x, kvh = h >> 2;
  const int qrow = qb * 64 + w * 16 + r;

  const short* qp = q + (size_t)qrow * qld + h * 64;
  bf16x8 qf0 = *reinterpret_cast<const bf16x8*>(qp + g * 8);
  bf16x8 qf1 = *reinterpret_cast<const bf16x8*>(qp + 32 + g * 8);

  const short* kbase = k + kvh * 64;                   // + s*kld
  const short* vbase = vt + (size_t)kvh * 64 * 2048;   // + d*2048 + s

  f32x4 oacc[4];
#pragma unroll
  for (int i = 0; i < 4; ++i) { f32x4 z = {0.f, 0.f, 0.f, 0.f}; oacc[i] = z; }
  float m_run = -INFINITY, l_run = 0.f;

  const int srow = w * 8 + (lane >> 3), schunk = lane & 7;

  // prologue: stage tile 0 into buffer 0
#pragma unroll
  for (int p = 0; p < 2; ++p) {
    const int rr = srow + 32 * p;
    const int cc = (schunk ^ (rr & 7)) << 3;
    gload16(kbase + (size_t)rr * kld + cc, (char*)Ks + p * 4096 + w * 1024);
    gload16(vbase + (size_t)rr * 2048 + cc, (char*)Vs + p * 4096 + w * 1024);
  }
  asm volatile("s_waitcnt vmcnt(0)" ::: "memory");
  __syncthreads();

  for (int it = 0; it < 32; ++it) {
    const int cur = it & 1;
    if (it < 31) {  // stage next tile into the other buffer
      const int s1 = (it + 1) * 64;
#pragma unroll
      for (int p = 0; p < 2; ++p) {
        const int rr = srow + 32 * p;
        const int cc = (schunk ^ (rr & 7)) << 3;
        gload16(kbase + (size_t)(s1 + rr) * kld + cc,
                (char*)Ks + (cur ^ 1) * 8192 + p * 4096 + w * 1024);
        gload16(vbase + (size_t)rr * 2048 + s1 + cc,
                (char*)Vs + (cur ^ 1) * 8192 + p * 4096 + w * 1024);
      }
    }
    const int s0 = it * 64;
    const short* Kc = Ks[cur];
    const short* Vc = Vs[cur];

    // S^T = K @ Q^T : lane holds S^T[s = st*16 + 4g + j][q = r]
    f32x4 sa[4];
#pragma unroll
    for (int st = 0; st < 4; ++st) {
      bf16x8 kf0 = *reinterpret_cast<const bf16x8*>(&Kc[swz(st * 16 + r, g * 8)]);
      bf16x8 kf1 = *reinterpret_cast<const bf16x8*>(&Kc[swz(st * 16 + r, 32 + g * 8)]);
      f32x4 z = {0.f, 0.f, 0.f, 0.f};
      z = mfma16(kf0, qf0, z);
      z = mfma16(kf1, qf1, z);
      sa[st] = z;
    }
    // online softmax (per q-row = r; reduce over g via shfl_xor 16,32)
    float sv[16];
    float pmax = -INFINITY;
#pragma unroll
    for (int st = 0; st < 4; ++st) {
      const float4 mv = *reinterpret_cast<const float4*>(mask + s0 + st * 16 + 4 * g);
#pragma unroll
      for (int j = 0; j < 4; ++j) {
        float xx = sa[st][j] + ((const float*)&mv)[j];
        sv[st * 4 + j] = xx;
        pmax = fmaxf(pmax, xx);
      }
    }
    pmax = fmaxf(pmax, __shfl_xor(pmax, 16));
    pmax = fmaxf(pmax, __shfl_xor(pmax, 32));
    float m_new = fmaxf(m_run, pmax);
    float corr = __expf(m_run - m_new);
    float psum = 0.f;
    short pb[16];
#pragma unroll
    for (int i = 0; i < 16; ++i) {
      float p = __expf(sv[i] - m_new);
      psum += p;
      pb[i] = f2bf(p);
    }
    psum += __shfl_xor(psum, 16);
    psum += __shfl_xor(psum, 32);
    l_run = l_run * corr + psum;
    m_run = m_new;
#pragma unroll
    for (int dt = 0; dt < 4; ++dt)
#pragma unroll
      for (int j = 0; j < 4; ++j) oacc[dt][j] *= corr;

    // O^T += V^T @ P^T; k-bijection s = 4g + (j&3) + 16*(j>>2) (+32*hs) on both operands
#pragma unroll
    for (int hs = 0; hs < 2; ++hs) {
      bf16x8 pf = { pb[hs * 8 + 0], pb[hs * 8 + 1], pb[hs * 8 + 2], pb[hs * 8 + 3],
                    pb[hs * 8 + 4], pb[hs * 8 + 5], pb[hs * 8 + 6], pb[hs * 8 + 7] };
#pragma unroll
      for (int dt = 0; dt < 4; ++dt) {
        int d = dt * 16 + r;
        int c1 = 4 * g + 32 * hs;
        bf16x4 va  = *reinterpret_cast<const bf16x4*>(&Vc[swz(d, c1)]);
        bf16x4 vb2 = *reinterpret_cast<const bf16x4*>(&Vc[swz(d, c1 + 16)]);
        bf16x8 vf = { va[0], va[1], va[2], va[3], vb2[0], vb2[1], vb2[2], vb2[3] };
        oacc[dt] = mfma16(vf, pf, oacc[dt]);
      }
    }
    asm volatile("s_waitcnt vmcnt(0)" ::: "memory");
    __syncthreads();
  }
  float inv = 1.f / l_run;
#pragma unroll
  for (int dt = 0; dt < 4; ++dt) {
    bf16x4 ov = { f2bf(oacc[dt][0] * inv), f2bf(oacc[dt][1] * inv),
                  f2bf(oacc[dt][2] * inv), f2bf(oacc[dt][3] * inv) };
    *reinterpret_cast<bf16x4*>(o + (size_t)qrow * 1024 + h * 64 + dt * 16 + 4 * g) = ov;
  }
}

// ---------- launch ----------
extern "C" void kernel_launch(void* const* d_in, const int* in_sizes, int n_in,
                              void* d_out, int out_size, void* d_ws, size_t ws_size,
                              hipStream_t stream) {
  const int*   ids   = (const int*)d_in[0];
  const float* mask  = (const float*)d_in[1];
  const float* tok   = (const float*)d_in[2];
  const float* pos   = (const float*)d_in[3];
  const float* qW    = (const float*)d_in[4];
  const float* qbias = (const float*)d_in[5];
  const float* kW    = (const float*)d_in[6];
  const float* kbias = (const float*)d_in[7];
  const float* vW    = (const float*)d_in[8];
  const float* vbias = (const float*)d_in[9];
  const float* oW    = (const float*)d_in[10];
  const float* obias = (const float*)d_in[11];
  const float* m1W   = (const float*)d_in[12];
  const float* m1b   = (const float*)d_in[13];
  const float* m2W   = (const float*)d_in[14];
  const float* m2b   = (const float*)d_in[15];
  const float* ln1g  = (const float*)d_in[16];
  const float* ln1b  = (const float*)d_in[17];
  const float* ln2g  = (const float*)d_in[18];
  const float* ln2b  = (const float*)d_in[19];
  const float* lnfg  = (const float*)d_in[20];
  const float* lnfb  = (const float*)d_in[21];
  const float* headW = (const float*)d_in[22];
  float* out = (float*)d_out;

  char* ws = (char*)d_ws;
  float* x   = (float*)ws;                        // 8 MB
  short* xb  = (short*)(ws + 8388608ull);         // 4 MB
  // vt aliases xb: xb (LN1 out) is dead between QKV-GEMM and LN2; vt lives only
  // between vtr_k and attn_k, strictly inside that window.
  short* vt  = (short*)(ws + 8388608ull);         // 1 MB alias

  const size_t OFF_QKV  = 12582912ull;   // 6 MB  bf16 [2048][1536]
  const size_t OFF_AO   = 18874368ull;   // 4 MB
  const size_t OFF_FF   = 23068672ull;   // 16 MB
  const size_t OFF_BQ   = 39845888ull;   // 24 KB f32 [4][1536]
  const size_t OFF_WQKV = 39870464ull;   // 12 MB bf16 [4][1536][1024]
  const size_t OFF_WO   = 52453376ull;   // 8 MB  bf16 [4][1024][1024]
  const size_t OFF_WM1  = 60841984ull;   // 32 MB bf16 [4][4096][1024]
  const size_t OFF_WM2  = 94396416ull;   // 32 MB bf16 [4][1024][4096]
  const size_t OFF_WH   = 127950848ull;  // 64 MB bf16 [32000][1024]
  const size_t NEED     = 193486848ull;

  if (ws_size >= NEED) {
    short* qkv  = (short*)(ws + OFF_QKV);
    short* ao   = (short*)(ws + OFF_AO);
    short* ff   = (short*)(ws + OFF_FF);
    float* bqv  = (float*)(ws + OFF_BQ);
    short* Wqkv = (short*)(ws + OFF_WQKV);
    short* Wo   = (short*)(ws + OFF_WO);
    short* Wm1  = (short*)(ws + OFF_WM1);
    short* Wm2  = (short*)(ws + OFF_WM2);
    short* Wh   = (short*)(ws + OFF_WH);

    tcvt_k<<<dim3(16, 16, 4), 256, 0, stream>>>(qW, Wqkv, 1024, 1048576ull, 1572864ull, 0, 1024, 0.125f);
    tcvt_k<<<dim3(4, 16, 4),  256, 0, stream>>>(kW, Wqkv, 256,  262144ull,  1572864ull, 1024, 1024, 1.f);
    tcvt_k<<<dim3(4, 16, 4),  256, 0, stream>>>(vW, Wqkv, 256,  262144ull,  1572864ull, 1280, 1024, 1.f);
    tcvt_k<<<dim3(16, 16, 4), 256, 0, stream>>>(oW, Wo, 1024, 1048576ull, 1048576ull, 0, 1024, 1.f);
    tcvt_k<<<dim3(64, 16, 4), 256, 0, stream>>>(m1W, Wm1, 4096, 4194304ull, 4194304ull, 0, 1024, 1.f);
    tcvt_k<<<dim3(16, 64, 4), 256, 0, stream>>>(m2W, Wm2, 1024, 4194304ull, 4194304ull, 0, 4096, 1.f);
    tcvt_k<<<dim3(500, 16, 1), 256, 0, stream>>>(headW, Wh, 32000, 0ull, 0ull, 0, 1024, 1.f);
    bqkv_k<<<dim3(6, 4), 256, 0, stream>>>(qbias, kbias, vbias, bqv);

    embed_k<<<2048, 256, 0, stream>>>(ids, tok, pos, x);

    for (int l = 0; l < 4; ++l) {
      short* Wq_l  = Wqkv + (size_t)l * 1536 * 1024;
      short* Wo_l  = Wo   + (size_t)l * 1024 * 1024;
      short* Wm1_l = Wm1  + (size_t)l * 4096 * 1024;
      short* Wm2_l = Wm2  + (size_t)l * 1024 * 4096;

      ln_k<<<2048, 256, 0, stream>>>(x, ln1g + l * 1024, ln1b + l * 1024, xb);
      gemm_bt<0, 0><<<dim3(12, 16), 256, 0, stream>>>(xb, Wq_l, bqv + l * 1536, nullptr,
                                                      qkv, 2048, 1536, 1024);
      vtr_k<<<dim3(32, 4), 256, 0, stream>>>(qkv + 1280, 1536, vt);
      attn_k<<<dim3(32, 16), 256, 0, stream>>>(qkv, 1536, qkv + 1024, 1536, vt, mask, ao);
      gemm_bt<2, 0><<<dim3(8, 16), 256, 0, stream>>>(ao, Wo_l, obias + l * 1024, x,
                                                     x, 2048, 1024, 1024);
      ln_k<<<2048, 256, 0, stream>>>(x, ln2g + l * 1024, ln2b + l * 1024, xb);
      gemm_bt<1, 0><<<dim3(32, 16), 256, 0, stream>>>(xb, Wm1_l, m1b + l * 4096, nullptr,
                                                      ff, 2048, 4096, 1024);
      gemm_bt<2, 0><<<dim3(8, 16), 256, 0, stream>>>(ff, Wm2_l, m2b + l * 1024, x,
                                                     x, 2048, 1024, 4096);
    }
    ln_k<<<2048, 256, 0, stream>>>(x, lnfg, lnfb, xb);
    gemm_bt<3, 1><<<dim3(250, 16), 256, 0, stream>>>(xb, Wh, nullptr, nullptr,
                                                     out, 2048, 32000, 1024);
  } else {
    // fallback: f32-weight GEMMs, needs < 39 MB ws
    short* qbf = (short*)(ws + (12u << 20));
    short* kbf = (short*)(ws + (16u << 20));
    short* vbf = (short*)(ws + (17u << 20));
    short* ao  = (short*)(ws + (18u << 20));
    short* ff  = (short*)(ws + (22u << 20));
    short* vtf = (short*)(ws + (38u << 20));

    embed_k<<<2048, 256, 0, stream>>>(ids, tok, pos, x);
    for (int l = 0; l < 4; ++l) {
      ln_k<<<2048, 256, 0, stream>>>(x, ln1g + l * 1024, ln1b + l * 1024, xb);
      gemm_k<0><<<dim3(8, 16), 256, 0, stream>>>(xb, qW + (size_t)l * 1024 * 1024,
          qbias + l * 1024, nullptr, qbf, 2048, 1024, 1024, 0.125f);
      gemm_k<0><<<dim3(2, 16), 256, 0, stream>>>(xb, kW + (size_t)l * 1024 * 256,
          kbias + l * 256, nullptr, kbf, 2048, 256, 1024, 1.f);
      gemm_k<0><<<dim3(2, 16), 256, 0, stream>>>(xb, vW + (size_t)l * 1024 * 256,
          vbias + l * 256, nullptr, vbf, 2048, 256, 1024, 1.f);
      vtr_k<<<dim3(32, 4), 256, 0, stream>>>(vbf, 256, vtf);
      attn_k<<<dim3(32, 16), 256, 0, stream>>>(qbf, 1024, kbf, 256, vtf, mask, ao);
      gemm_k<2><<<dim3(8, 16), 256, 0, stream>>>(ao, oW + (size_t)l * 1024 * 1024,
          obias + l * 1024, x, x, 2048, 1024, 1024, 1.f);
      ln_k<<<2048, 256, 0, stream>>>(x, ln2g + l * 1024, ln2b + l * 1024, xb);
      gemm_k<1><<<dim3(32, 16), 256, 0, stream>>>(xb, m1W + (size_t)l * 1024 * 4096,
          m1b + l * 4096, nullptr, ff, 2048, 4096, 1024, 1.f);
      gemm_k<2><<<dim3(8, 16), 256, 0, stream>>>(ff, m2W + (size_t)l * 4096 * 1024,
          m2b + l * 1024, x, x, 2048, 1024, 4096, 1.f);
    }
    ln_k<<<2048, 256, 0, stream>>>(x, lnfg, lnfb, xb);
    gemm_k<3><<<dim3(250, 16), 256, 0, stream>>>(xb, headW, nullptr, nullptr, out,
        2048, 32000, 1024, 1.f);
  }
}

// Round 4
// 1302.234 us; speedup vs baseline: 3.2592x; 1.0291x over previous
//
#include <hip/hip_runtime.h>
#include <stdint.h>
#include <math.h>

// ---------- types ----------
typedef __attribute__((ext_vector_type(8))) short bf16x8;   // 8 bf16 (4 VGPR)
typedef __attribute__((ext_vector_type(4))) short bf16x4;
typedef __attribute__((ext_vector_type(4))) float f32x4;

__device__ __forceinline__ short f2bf(float f) {
  unsigned u = __builtin_bit_cast(unsigned, f);
  unsigned r = u + 0x7fffu + ((u >> 16) & 1u);
  return (short)(r >> 16);
}

__device__ __forceinline__ f32x4 mfma16(bf16x8 a, bf16x8 b, f32x4 c) {
  return __builtin_amdgcn_mfma_f32_16x16x32_bf16(a, b, c, 0, 0, 0);
}

// async global->LDS, 16B per lane. LDS dest = wave-uniform base + lane*16.
__device__ __forceinline__ void gload16(const void* g, void* l) {
  __builtin_amdgcn_global_load_lds((const __attribute__((address_space(1))) void*)g,
                                   (__attribute__((address_space(3))) void*)l, 16, 0, 0);
}

// LDS tile index: row-major [rows][64] bf16, 16B-chunk XOR swizzle on row&7.
__device__ __forceinline__ int swz(int row, int col) {
  return row * 64 + (((col >> 3) ^ (row & 7)) << 3) + (col & 7);
}

// ---------- embedding ----------
__global__ __launch_bounds__(256) void embed_k(const int* __restrict__ ids,
                                               const float* __restrict__ tok,
                                               const float* __restrict__ pos,
                                               float* __restrict__ x) {
  int row = blockIdx.x, t = threadIdx.x;
  int id = ids[row];
  const float4 a = *reinterpret_cast<const float4*>(tok + (size_t)id * 1024 + t * 4);
  const float4 b = *reinterpret_cast<const float4*>(pos + (size_t)row * 1024 + t * 4);
  float4 o = make_float4(a.x + b.x, a.y + b.y, a.z + b.z, a.w + b.w);
  *reinterpret_cast<float4*>(x + (size_t)row * 1024 + t * 4) = o;
}

// ---------- layernorm (f32 in, bf16 out) ----------
__global__ __launch_bounds__(256) void ln_k(const float* __restrict__ x,
                                            const float* __restrict__ gw,
                                            const float* __restrict__ bw,
                                            short* __restrict__ out) {
  int row = blockIdx.x, t = threadIdx.x;
  const float4 v = *reinterpret_cast<const float4*>(x + (size_t)row * 1024 + t * 4);
  float s = v.x + v.y + v.z + v.w;
  float q = v.x * v.x + v.y * v.y + v.z * v.z + v.w * v.w;
#pragma unroll
  for (int o = 32; o > 0; o >>= 1) { s += __shfl_xor(s, o); q += __shfl_xor(q, o); }
  __shared__ float sh[8];
  int w = t >> 6;
  if ((t & 63) == 0) { sh[w] = s; sh[4 + w] = q; }
  __syncthreads();
  float ts = sh[0] + sh[1] + sh[2] + sh[3];
  float tq = sh[4] + sh[5] + sh[6] + sh[7];
  float mean = ts * (1.f / 1024.f);
  float var  = tq * (1.f / 1024.f) - mean * mean;
  float rstd = rsqrtf(var + 1e-5f);
  const float4 gv = *reinterpret_cast<const float4*>(gw + t * 4);
  const float4 bv = *reinterpret_cast<const float4*>(bw + t * 4);
  bf16x4 ov = { f2bf((v.x - mean) * rstd * gv.x + bv.x),
                f2bf((v.y - mean) * rstd * gv.y + bv.y),
                f2bf((v.z - mean) * rstd * gv.z + bv.z),
                f2bf((v.w - mean) * rstd * gv.w + bv.w) };
  *reinterpret_cast<bf16x4*>(out + (size_t)row * 1024 + t * 4) = ov;
}

// ---------- weight transpose + f32->bf16 convert ----------
// 128k x 64n tile: 1KB-coalesced row reads, 64B/lane writes.
// W f32 [K,N] (layer z) -> Wt bf16 [rowOff+N][ldOut], Wt[n][k] = W[k][n]*scale
__global__ __launch_bounds__(256) void tcvt_k(const float* __restrict__ W,
                                              short* __restrict__ Wt,
                                              int N, size_t inStride, size_t outStride,
                                              int rowOff, int ldOut, float scale) {
  __shared__ float T[128][68];
  const float* Win = W + blockIdx.z * inStride;
  short* Wout = Wt + blockIdx.z * outStride;
  const int n0 = blockIdx.x * 64, k0 = blockIdx.y * 128;
  const int t = threadIdx.x;
  const int nc = (t & 15) * 4, kr = t >> 4;
#pragma unroll
  for (int p = 0; p < 8; ++p) {
    const float4 v = *reinterpret_cast<const float4*>(Win + (size_t)(k0 + kr + 16 * p) * N + n0 + nc);
    T[kr + 16 * p][nc + 0] = v.x;
    T[kr + 16 * p][nc + 1] = v.y;
    T[kr + 16 * p][nc + 2] = v.z;
    T[kr + 16 * p][nc + 3] = v.w;
  }
  __syncthreads();
  const int n = t >> 2, ks = (t & 3) * 32;
  short tmp[32];
#pragma unroll
  for (int i = 0; i < 32; ++i) tmp[i] = f2bf(T[ks + i][n] * scale);
  short* op = Wout + (size_t)(rowOff + n0 + n) * ldOut + k0 + ks;
#pragma unroll
  for (int c = 0; c < 4; ++c)
    *reinterpret_cast<bf16x8*>(op + c * 8) = *reinterpret_cast<bf16x8*>(tmp + c * 8);
}

// concat qkv bias (q scaled by 0.125)
__global__ __launch_bounds__(256) void bqkv_k(const float* __restrict__ qb,
                                              const float* __restrict__ kb,
                                              const float* __restrict__ vb,
                                              float* __restrict__ o) {
  int l = blockIdx.y;
  int c = blockIdx.x * 256 + threadIdx.x;
  float v;
  if (c < 1024) v = qb[l * 1024 + c] * 0.125f;
  else if (c < 1280) v = kb[l * 256 + c - 1024];
  else v = vb[l * 256 + c - 1280];
  o[l * 1536 + c] = v;
}

// ---------- V transpose (fallback path only) ----------
__global__ __launch_bounds__(256) void vtr_k(const short* __restrict__ v, int vld,
                                             short* __restrict__ vt) {
  __shared__ short T[64][80];
  const int kvh = blockIdx.y;
  const int s0 = blockIdx.x * 64;
  const int t = threadIdx.x;
  const int row = t >> 3, ch = t & 7;
#pragma unroll
  for (int p = 0; p < 2; ++p) {
    int s = row + 32 * p;
    bf16x8 vv = *reinterpret_cast<const bf16x8*>(v + (size_t)(s0 + s) * vld + kvh * 64 + ch * 8);
    *reinterpret_cast<bf16x8*>(&T[s][ch * 8]) = vv;
  }
  __syncthreads();
#pragma unroll
  for (int p = 0; p < 2; ++p) {
    int d = row + 32 * p;
    short tmp[8];
#pragma unroll
    for (int i = 0; i < 8; ++i) tmp[i] = T[ch * 8 + i][d];
    *reinterpret_cast<bf16x8*>(vt + (size_t)(kvh * 64 + d) * 2048 + s0 + ch * 8) =
        *reinterpret_cast<bf16x8*>(tmp);
  }
}

// ---------- GEMM (m97 structure): C[M,N] = A_bf16[M,K] @ Wt_bf16[N,K]^T ----------
// EPI: 0 bf16 out (acc+bias); 1 bf16 GELU(acc+bias); 2 f32 resid+acc+bias;
//      3 f32 acc; 4 = EPI0 + transposed-V scatter (cols>=1280 -> vt[(col-1280)][row])
// XSWZ: 0 identity; 1 m-fastest bijective XCD chunking (L2 W-panel reuse)
template <int EPI, int XSWZ>
__global__ __launch_bounds__(256, 4)
void gemm_bt(const short* __restrict__ A, const short* __restrict__ Wt,
             const float* __restrict__ bias, const float* __restrict__ resid,
             void* __restrict__ out, int M, int N, int K, int nbOff,
             short* __restrict__ vt) {
  __shared__ short As[128 * 64];
  __shared__ short Bs[128 * 64];
  const int t = threadIdx.x;
  const int lane = t & 63, w = t >> 6;
  const int g = lane >> 4, r = lane & 15;
  const int wr = w >> 1, wc = w & 1;

  int bx = blockIdx.x, by = blockIdx.y;
  if (XSWZ == 1) {
    const int nbx = gridDim.x, nby = gridDim.y, nwg = nbx * nby;
    const int bid = by * nbx + bx;
    const int q = nwg >> 3, rr = nwg & 7;
    const int xcd = bid & 7, loc = bid >> 3;
    const int sw = (xcd < rr ? xcd * (q + 1) : rr * (q + 1) + (xcd - rr) * q) + loc;
    by = sw % nby; bx = sw / nby;  // m-fastest: XCD-contiguous blocks share an n-panel
  }
  const int m0 = by * 128, n0 = (bx + nbOff) * 128;

  f32x4 acc[4][4];
#pragma unroll
  for (int i = 0; i < 4; ++i)
#pragma unroll
    for (int j = 0; j < 4; ++j) { f32x4 z = {0.f, 0.f, 0.f, 0.f}; acc[i][j] = z; }

  const int srow = lane >> 3, sslot = lane & 7;

  for (int k0 = 0; k0 < K; k0 += 64) {
#pragma unroll
    for (int i = 0; i < 4; ++i) {
      const int rowA = w * 32 + i * 8 + srow;
      const int colA = (sslot ^ (srow & 7)) << 3;
      gload16(A + (size_t)(m0 + rowA) * K + k0 + colA, &As[(w * 32 + i * 8) * 64]);
    }
#pragma unroll
    for (int i = 0; i < 4; ++i) {
      const int rowB = w * 32 + i * 8 + srow;
      const int colB = (sslot ^ (srow & 7)) << 3;
      gload16(Wt + (size_t)(n0 + rowB) * K + k0 + colB, &Bs[(w * 32 + i * 8) * 64]);
    }
    __syncthreads();
#pragma unroll
    for (int kk = 0; kk < 64; kk += 32) {
      bf16x8 af[4], bfg[4];
#pragma unroll
      for (int mt = 0; mt < 4; ++mt)
        af[mt] = *reinterpret_cast<const bf16x8*>(&As[swz(wr * 64 + mt * 16 + r, kk + g * 8)]);
#pragma unroll
      for (int nt = 0; nt < 4; ++nt)
        bfg[nt] = *reinterpret_cast<const bf16x8*>(&Bs[swz(wc * 64 + nt * 16 + r, kk + g * 8)]);
#pragma unroll
      for (int mt = 0; mt < 4; ++mt)
#pragma unroll
        for (int nt = 0; nt < 4; ++nt)
          acc[mt][nt] = mfma16(af[mt], bfg[nt], acc[mt][nt]);
    }
    __syncthreads();
  }
#pragma unroll
  for (int nt = 0; nt < 4; ++nt) {
    const int col = n0 + wc * 64 + nt * 16 + r;
    const float bv = (EPI == 3) ? 0.f : bias[col];
#pragma unroll
    for (int mt = 0; mt < 4; ++mt) {
#pragma unroll
      for (int j = 0; j < 4; ++j) {
        const int row = m0 + wr * 64 + mt * 16 + 4 * g + j;
        const size_t oi = (size_t)row * N + col;
        float vv = acc[mt][nt][j] + bv;
        if (EPI == 0) {
          ((short*)out)[oi] = f2bf(vv);
        } else if (EPI == 1) {
          vv = 0.5f * vv * (1.f + erff(vv * 0.70710678118654752f));
          ((short*)out)[oi] = f2bf(vv);
        } else if (EPI == 2) {
          ((float*)out)[oi] = resid[oi] + vv;
        } else if (EPI == 3) {
          ((float*)out)[oi] = vv;
        } else {  // EPI 4
          short bb = f2bf(vv);
          ((short*)out)[oi] = bb;
          if (col >= 1280) vt[(size_t)(col - 1280) * 2048 + row] = bb;
        }
      }
    }
  }
}

// ---------- legacy GEMM (f32 weights) — fallback if ws too small ----------
template <int EPI>
__global__ __launch_bounds__(256)
void gemm_k(const short* __restrict__ A, const float* __restrict__ W,
            const float* __restrict__ bias, const float* resid, void* out,
            int M, int N, int K, float scale) {
  __shared__ short As[128 * 64];
  __shared__ short Bs[128 * 64];
  const int t = threadIdx.x;
  const int lane = t & 63;
  const int g = lane >> 4, r = lane & 15;
  const int wid = t >> 6, wr = wid >> 1, wc = wid & 1;
  const int m0 = blockIdx.y * 128, n0 = blockIdx.x * 128;
  f32x4 acc[4][4];
#pragma unroll
  for (int i = 0; i < 4; ++i)
#pragma unroll
    for (int j = 0; j < 4; ++j) { f32x4 z = {0.f, 0.f, 0.f, 0.f}; acc[i][j] = z; }
  const int arow = t >> 3, ac = t & 7;
  const int bnn = t >> 1, bkh = t & 1;
  for (int k0 = 0; k0 < K; k0 += 64) {
#pragma unroll
    for (int p = 0; p < 4; ++p) {
      int row = arow + 32 * p;
      bf16x8 av = *reinterpret_cast<const bf16x8*>(A + (size_t)(m0 + row) * K + k0 + ac * 8);
      *reinterpret_cast<bf16x8*>(&As[swz(row, ac * 8)]) = av;
    }
#pragma unroll
    for (int p = 0; p < 8; ++p) {
      int kg = 4 * (bkh + 2 * p);
      const float* wp = W + (size_t)(k0 + kg) * N + n0 + bnn;
      bf16x4 wv = { f2bf(wp[0]), f2bf(wp[(size_t)N]), f2bf(wp[(size_t)2 * N]), f2bf(wp[(size_t)3 * N]) };
      *reinterpret_cast<bf16x4*>(&Bs[swz(bnn, kg)]) = wv;
    }
    __syncthreads();
#pragma unroll
    for (int kk = 0; kk < 64; kk += 32) {
      bf16x8 af[4], bfg[4];
#pragma unroll
      for (int mt = 0; mt < 4; ++mt)
        af[mt] = *reinterpret_cast<const bf16x8*>(&As[swz(wr * 64 + mt * 16 + r, kk + g * 8)]);
#pragma unroll
      for (int nt = 0; nt < 4; ++nt)
        bfg[nt] = *reinterpret_cast<const bf16x8*>(&Bs[swz(wc * 64 + nt * 16 + r, kk + g * 8)]);
#pragma unroll
      for (int mt = 0; mt < 4; ++mt)
#pragma unroll
        for (int nt = 0; nt < 4; ++nt)
          acc[mt][nt] = mfma16(af[mt], bfg[nt], acc[mt][nt]);
    }
    __syncthreads();
  }
#pragma unroll
  for (int nt = 0; nt < 4; ++nt) {
    const int col = n0 + wc * 64 + nt * 16 + r;
    const float bv = (EPI == 3) ? 0.f : bias[col];
#pragma unroll
    for (int mt = 0; mt < 4; ++mt) {
#pragma unroll
      for (int j = 0; j < 4; ++j) {
        const int row = m0 + wr * 64 + mt * 16 + 4 * g + j;
        const size_t oi = (size_t)row * N + col;
        float vv = acc[mt][nt][j] + bv;
        if (EPI == 0) {
          ((short*)out)[oi] = f2bf(vv * scale);
        } else if (EPI == 1) {
          vv = 0.5f * vv * (1.f + erff(vv * 0.70710678118654752f));
          ((short*)out)[oi] = f2bf(vv);
        } else if (EPI == 2) {
          ((float*)out)[oi] = resid[oi] + vv;
        } else {
          ((float*)out)[oi] = vv;
        }
      }
    }
  }
}

// ---------- flash-style GQA attention (dbuf, gload_lds staging) ----------
__global__ __launch_bounds__(256) void attn_k(const short* __restrict__ q, int qld,
                                              const short* __restrict__ k, int kld,
                                              const short* __restrict__ vt,
                                              const float* __restrict__ mask,
                                              short* __restrict__ o) {
  __shared__ short Ks[2][64 * 64];  // [s][d], 16B-chunk swizzled
  __shared__ short Vs[2][64 * 64];  // [d][s], 16B-chunk swizzled
  const int t = threadIdx.x, lane = t & 63, w = t >> 6;
  const int g = lane >> 4, r = lane & 15;
  const int h = blockIdx.y, qb = blockIdx.x, kvh = h >> 2;
  const int qrow = qb * 64 + w * 16 + r;

  const short* qp = q + (size_t)qrow * qld + h * 64;
  bf16x8 qf0 = *reinterpret_cast<const bf16x8*>(qp + g * 8);
  bf16x8 qf1 = *reinterpret_cast<const bf16x8*>(qp + 32 + g * 8);

  const short* kbase = k + kvh * 64;                   // + s*kld
  const short* vbase = vt + (size_t)kvh * 64 * 2048;   // + d*2048 + s

  f32x4 oacc[4];
#pragma unroll
  for (int i = 0; i < 4; ++i) { f32x4 z = {0.f, 0.f, 0.f, 0.f}; oacc[i] = z; }
  float m_run = -INFINITY, l_run = 0.f;

  const int srow = w * 8 + (lane >> 3), schunk = lane & 7;

#pragma unroll
  for (int p = 0; p < 2; ++p) {
    const int rr = srow + 32 * p;
    const int cc = (schunk ^ (rr & 7)) << 3;
    gload16(kbase + (size_t)rr * kld + cc, (char*)Ks + p * 4096 + w * 1024);
    gload16(vbase + (size_t)rr * 2048 + cc, (char*)Vs + p * 4096 + w * 1024);
  }
  asm volatile("s_waitcnt vmcnt(0)" ::: "memory");
  __syncthreads();

  for (int it = 0; it < 32; ++it) {
    const int cur = it & 1;
    if (it < 31) {
      const int s1 = (it + 1) * 64;
#pragma unroll
      for (int p = 0; p < 2; ++p) {
        const int rr = srow + 32 * p;
        const int cc = (schunk ^ (rr & 7)) << 3;
        gload16(kbase + (size_t)(s1 + rr) * kld + cc,
                (char*)Ks + (cur ^ 1) * 8192 + p * 4096 + w * 1024);
        gload16(vbase + (size_t)rr * 2048 + s1 + cc,
                (char*)Vs + (cur ^ 1) * 8192 + p * 4096 + w * 1024);
      }
    }
    const int s0 = it * 64;
    const short* Kc = Ks[cur];
    const short* Vc = Vs[cur];

    f32x4 sa[4];
#pragma unroll
    for (int st = 0; st < 4; ++st) {
      bf16x8 kf0 = *reinterpret_cast<const bf16x8*>(&Kc[swz(st * 16 + r, g * 8)]);
      bf16x8 kf1 = *reinterpret_cast<const bf16x8*>(&Kc[swz(st * 16 + r, 32 + g * 8)]);
      f32x4 z = {0.f, 0.f, 0.f, 0.f};
      z = mfma16(kf0, qf0, z);
      z = mfma16(kf1, qf1, z);
      sa[st] = z;
    }
    float sv[16];
    float pmax = -INFINITY;
#pragma unroll
    for (int st = 0; st < 4; ++st) {
      const float4 mv = *reinterpret_cast<const float4*>(mask + s0 + st * 16 + 4 * g);
#pragma unroll
      for (int j = 0; j < 4; ++j) {
        float xx = sa[st][j] + ((const float*)&mv)[j];
        sv[st * 4 + j] = xx;
        pmax = fmaxf(pmax, xx);
      }
    }
    pmax = fmaxf(pmax, __shfl_xor(pmax, 16));
    pmax = fmaxf(pmax, __shfl_xor(pmax, 32));
    float m_new = fmaxf(m_run, pmax);
    float corr = __expf(m_run - m_new);
    float psum = 0.f;
    short pb[16];
#pragma unroll
    for (int i = 0; i < 16; ++i) {
      float p = __expf(sv[i] - m_new);
      psum += p;
      pb[i] = f2bf(p);
    }
    psum += __shfl_xor(psum, 16);
    psum += __shfl_xor(psum, 32);
    l_run = l_run * corr + psum;
    m_run = m_new;
#pragma unroll
    for (int dt = 0; dt < 4; ++dt)
#pragma unroll
      for (int j = 0; j < 4; ++j) oacc[dt][j] *= corr;

#pragma unroll
    for (int hs = 0; hs < 2; ++hs) {
      bf16x8 pf = { pb[hs * 8 + 0], pb[hs * 8 + 1], pb[hs * 8 + 2], pb[hs * 8 + 3],
                    pb[hs * 8 + 4], pb[hs * 8 + 5], pb[hs * 8 + 6], pb[hs * 8 + 7] };
#pragma unroll
      for (int dt = 0; dt < 4; ++dt) {
        int d = dt * 16 + r;
        int c1 = 4 * g + 32 * hs;
        bf16x4 va  = *reinterpret_cast<const bf16x4*>(&Vc[swz(d, c1)]);
        bf16x4 vb2 = *reinterpret_cast<const bf16x4*>(&Vc[swz(d, c1 + 16)]);
        bf16x8 vf = { va[0], va[1], va[2], va[3], vb2[0], vb2[1], vb2[2], vb2[3] };
        oacc[dt] = mfma16(vf, pf, oacc[dt]);
      }
    }
    asm volatile("s_waitcnt vmcnt(0)" ::: "memory");
    __syncthreads();
  }
  float inv = 1.f / l_run;
#pragma unroll
  for (int dt = 0; dt < 4; ++dt) {
    bf16x4 ov = { f2bf(oacc[dt][0] * inv), f2bf(oacc[dt][1] * inv),
                  f2bf(oacc[dt][2] * inv), f2bf(oacc[dt][3] * inv) };
    *reinterpret_cast<bf16x4*>(o + (size_t)qrow * 1024 + h * 64 + dt * 16 + 4 * g) = ov;
  }
}

// ---------- launch ----------
extern "C" void kernel_launch(void* const* d_in, const int* in_sizes, int n_in,
                              void* d_out, int out_size, void* d_ws, size_t ws_size,
                              hipStream_t stream) {
  const int*   ids   = (const int*)d_in[0];
  const float* mask  = (const float*)d_in[1];
  const float* tok   = (const float*)d_in[2];
  const float* pos   = (const float*)d_in[3];
  const float* qW    = (const float*)d_in[4];
  const float* qbias = (const float*)d_in[5];
  const float* kW    = (const float*)d_in[6];
  const float* kbias = (const float*)d_in[7];
  const float* vW    = (const float*)d_in[8];
  const float* vbias = (const float*)d_in[9];
  const float* oW    = (const float*)d_in[10];
  const float* obias = (const float*)d_in[11];
  const float* m1W   = (const float*)d_in[12];
  const float* m1b   = (const float*)d_in[13];
  const float* m2W   = (const float*)d_in[14];
  const float* m2b   = (const float*)d_in[15];
  const float* ln1g  = (const float*)d_in[16];
  const float* ln1b  = (const float*)d_in[17];
  const float* ln2g  = (const float*)d_in[18];
  const float* ln2b  = (const float*)d_in[19];
  const float* lnfg  = (const float*)d_in[20];
  const float* lnfb  = (const float*)d_in[21];
  const float* headW = (const float*)d_in[22];
  float* out = (float*)d_out;

  char* ws = (char*)d_ws;
  float* x   = (float*)ws;                        // 8 MB
  short* xb  = (short*)(ws + 8388608ull);         // 4 MB

  const size_t OFF_QKV  = 12582912ull;   // 6 MB  bf16 [2048][1536]
  const size_t OFF_AO   = 18874368ull;   // 4 MB
  const size_t OFF_FF   = 23068672ull;   // 16 MB (first 1 MB aliased as vt between QKV-GEMM and attn)
  const size_t OFF_BQ   = 39845888ull;   // 24 KB f32 [4][1536]
  const size_t OFF_WQKV = 39870464ull;   // 12 MB bf16 [4][1536][1024]
  const size_t OFF_WO   = 52453376ull;   // 8 MB  bf16 [4][1024][1024]
  const size_t OFF_WM1  = 60841984ull;   // 32 MB bf16 [4][4096][1024]
  const size_t OFF_WM2  = 94396416ull;   // 32 MB bf16 [4][1024][4096]
  const size_t OFF_WH   = 127950848ull;  // 64 MB bf16 [32000][1024]
  const size_t NEED     = 193486848ull;

  if (ws_size >= NEED) {
    short* qkv  = (short*)(ws + OFF_QKV);
    short* ao   = (short*)(ws + OFF_AO);
    short* ff   = (short*)(ws + OFF_FF);
    short* vt   = ff;  // alias: ff dead during QKV->attn window
    float* bqv  = (float*)(ws + OFF_BQ);
    short* Wqkv = (short*)(ws + OFF_WQKV);
    short* Wo   = (short*)(ws + OFF_WO);
    short* Wm1  = (short*)(ws + OFF_WM1);
    short* Wm2  = (short*)(ws + OFF_WM2);
    short* Wh   = (short*)(ws + OFF_WH);

    tcvt_k<<<dim3(16, 8, 4), 256, 0, stream>>>(qW, Wqkv, 1024, 1048576ull, 1572864ull, 0, 1024, 0.125f);
    tcvt_k<<<dim3(4, 8, 4),  256, 0, stream>>>(kW, Wqkv, 256,  262144ull,  1572864ull, 1024, 1024, 1.f);
    tcvt_k<<<dim3(4, 8, 4),  256, 0, stream>>>(vW, Wqkv, 256,  262144ull,  1572864ull, 1280, 1024, 1.f);
    tcvt_k<<<dim3(16, 8, 4), 256, 0, stream>>>(oW, Wo, 1024, 1048576ull, 1048576ull, 0, 1024, 1.f);
    tcvt_k<<<dim3(64, 8, 4), 256, 0, stream>>>(m1W, Wm1, 4096, 4194304ull, 4194304ull, 0, 1024, 1.f);
    tcvt_k<<<dim3(16, 32, 4), 256, 0, stream>>>(m2W, Wm2, 1024, 4194304ull, 4194304ull, 0, 4096, 1.f);
    tcvt_k<<<dim3(500, 8, 1), 256, 0, stream>>>(headW, Wh, 32000, 0ull, 0ull, 0, 1024, 1.f);
    bqkv_k<<<dim3(6, 4), 256, 0, stream>>>(qbias, kbias, vbias, bqv);

    embed_k<<<2048, 256, 0, stream>>>(ids, tok, pos, x);

    for (int l = 0; l < 4; ++l) {
      short* Wq_l  = Wqkv + (size_t)l * 1536 * 1024;
      short* Wo_l  = Wo   + (size_t)l * 1024 * 1024;
      short* Wm1_l = Wm1  + (size_t)l * 4096 * 1024;
      short* Wm2_l = Wm2  + (size_t)l * 1024 * 4096;

      ln_k<<<2048, 256, 0, stream>>>(x, ln1g + l * 1024, ln1b + l * 1024, xb);
      gemm_bt<4, 0><<<dim3(12, 16), 256, 0, stream>>>(xb, Wq_l, bqv + l * 1536, nullptr,
                                                      qkv, 2048, 1536, 1024, 0, vt);
      attn_k<<<dim3(32, 16), 256, 0, stream>>>(qkv, 1536, qkv + 1024, 1536, vt, mask, ao);
      gemm_bt<2, 0><<<dim3(8, 16), 256, 0, stream>>>(ao, Wo_l, obias + l * 1024, x,
                                                     x, 2048, 1024, 1024, 0, nullptr);
      ln_k<<<2048, 256, 0, stream>>>(x, ln2g + l * 1024, ln2b + l * 1024, xb);
      gemm_bt<1, 1><<<dim3(32, 16), 256, 0, stream>>>(xb, Wm1_l, m1b + l * 4096, nullptr,
                                                      ff, 2048, 4096, 1024, 0, nullptr);
      gemm_bt<2, 1><<<dim3(8, 16), 256, 0, stream>>>(ff, Wm2_l, m2b + l * 1024, x,
                                                     x, 2048, 1024, 4096, 0, nullptr);
    }
    ln_k<<<2048, 256, 0, stream>>>(x, lnfg, lnfb, xb);
    gemm_bt<3, 1><<<dim3(125, 16), 256, 0, stream>>>(xb, Wh, nullptr, nullptr,
                                                     out, 2048, 32000, 1024, 0, nullptr);
    gemm_bt<3, 1><<<dim3(125, 16), 256, 0, stream>>>(xb, Wh, nullptr, nullptr,
                                                     out, 2048, 32000, 1024, 125, nullptr);
  } else {
    // fallback: f32-weight GEMMs, needs < 40 MB ws
    short* qbf = (short*)(ws + (12u << 20));
    short* kbf = (short*)(ws + (16u << 20));
    short* vbf = (short*)(ws + (17u << 20));
    short* ao  = (short*)(ws + (18u << 20));
    short* ff  = (short*)(ws + (22u << 20));
    short* vtf = (short*)(ws + (38u << 20));

    embed_k<<<2048, 256, 0, stream>>>(ids, tok, pos, x);
    for (int l = 0; l < 4; ++l) {
      ln_k<<<2048, 256, 0, stream>>>(x, ln1g + l * 1024, ln1b + l * 1024, xb);
      gemm_k<0><<<dim3(8, 16), 256, 0, stream>>>(xb, qW + (size_t)l * 1024 * 1024,
          qbias + l * 1024, nullptr, qbf, 2048, 1024, 1024, 0.125f);
      gemm_k<0><<<dim3(2, 16), 256, 0, stream>>>(xb, kW + (size_t)l * 1024 * 256,
          kbias + l * 256, nullptr, kbf, 2048, 256, 1024, 1.f);
      gemm_k<0><<<dim3(2, 16), 256, 0, stream>>>(xb, vW + (size_t)l * 1024 * 256,
          vbias + l * 256, nullptr, vbf, 2048, 256, 1024, 1.f);
      vtr_k<<<dim3(32, 4), 256, 0, stream>>>(vbf, 256, vtf);
      attn_k<<<dim3(32, 16), 256, 0, stream>>>(qbf, 1024, kbf, 256, vtf, mask, ao);
      gemm_k<2><<<dim3(8, 16), 256, 0, stream>>>(ao, oW + (size_t)l * 1024 * 1024,
          obias + l * 1024, x, x, 2048, 1024, 1024, 1.f);
      ln_k<<<2048, 256, 0, stream>>>(x, ln2g + l * 1024, ln2b + l * 1024, xb);
      gemm_k<1><<<dim3(32, 16), 256, 0, stream>>>(xb, m1W + (size_t)l * 1024 * 4096,
          m1b + l * 4096, nullptr, ff, 2048, 4096, 1024, 1.f);
      gemm_k<2><<<dim3(8, 16), 256, 0, stream>>>(ff, m2W + (size_t)l * 4096 * 1024,
          m2b + l * 1024, x, x, 2048, 1024, 4096, 1.f);
    }
    ln_k<<<2048, 256, 0, stream>>>(x, lnfg, lnfb, xb);
    gemm_k<3><<<dim3(250, 16), 256, 0, stream>>>(xb, headW, nullptr, nullptr, out,
        2048, 32000, 1024, 1.f);
  }
}

// Round 5
// 1191.452 us; speedup vs baseline: 3.5622x; 1.0930x over previous
//
#include <hip/hip_runtime.h>
#include <stdint.h>
#include <math.h>

// ---------- types ----------
typedef __attribute__((ext_vector_type(8))) short bf16x8;   // 8 bf16 (4 VGPR)
typedef __attribute__((ext_vector_type(4))) short bf16x4;
typedef __attribute__((ext_vector_type(4))) float f32x4;

__device__ __forceinline__ short f2bf(float f) {
  unsigned u = __builtin_bit_cast(unsigned, f);
  unsigned r = u + 0x7fffu + ((u >> 16) & 1u);
  return (short)(r >> 16);
}

__device__ __forceinline__ f32x4 mfma16(bf16x8 a, bf16x8 b, f32x4 c) {
  return __builtin_amdgcn_mfma_f32_16x16x32_bf16(a, b, c, 0, 0, 0);
}

// async global->LDS, 16B per lane. LDS dest = wave-uniform base + lane*16.
__device__ __forceinline__ void gload16(const void* g, void* l) {
  __builtin_amdgcn_global_load_lds((const __attribute__((address_space(1))) void*)g,
                                   (__attribute__((address_space(3))) void*)l, 16, 0, 0);
}

// LDS tile index: row-major [rows][64] bf16, 16B-chunk XOR swizzle on row&7.
__device__ __forceinline__ int swz(int row, int col) {
  return row * 64 + (((col >> 3) ^ (row & 7)) << 3) + (col & 7);
}

// ---------- embedding ----------
__global__ __launch_bounds__(256) void embed_k(const int* __restrict__ ids,
                                               const float* __restrict__ tok,
                                               const float* __restrict__ pos,
                                               float* __restrict__ x) {
  int row = blockIdx.x, t = threadIdx.x;
  int id = ids[row];
  const float4 a = *reinterpret_cast<const float4*>(tok + (size_t)id * 1024 + t * 4);
  const float4 b = *reinterpret_cast<const float4*>(pos + (size_t)row * 1024 + t * 4);
  float4 o = make_float4(a.x + b.x, a.y + b.y, a.z + b.z, a.w + b.w);
  *reinterpret_cast<float4*>(x + (size_t)row * 1024 + t * 4) = o;
}

// ---------- layernorm (f32 in, bf16 out) ----------
__global__ __launch_bounds__(256) void ln_k(const float* __restrict__ x,
                                            const float* __restrict__ gw,
                                            const float* __restrict__ bw,
                                            short* __restrict__ out) {
  int row = blockIdx.x, t = threadIdx.x;
  const float4 v = *reinterpret_cast<const float4*>(x + (size_t)row * 1024 + t * 4);
  float s = v.x + v.y + v.z + v.w;
  float q = v.x * v.x + v.y * v.y + v.z * v.z + v.w * v.w;
#pragma unroll
  for (int o = 32; o > 0; o >>= 1) { s += __shfl_xor(s, o); q += __shfl_xor(q, o); }
  __shared__ float sh[8];
  int w = t >> 6;
  if ((t & 63) == 0) { sh[w] = s; sh[4 + w] = q; }
  __syncthreads();
  float ts = sh[0] + sh[1] + sh[2] + sh[3];
  float tq = sh[4] + sh[5] + sh[6] + sh[7];
  float mean = ts * (1.f / 1024.f);
  float var  = tq * (1.f / 1024.f) - mean * mean;
  float rstd = rsqrtf(var + 1e-5f);
  const float4 gv = *reinterpret_cast<const float4*>(gw + t * 4);
  const float4 bv = *reinterpret_cast<const float4*>(bw + t * 4);
  bf16x4 ov = { f2bf((v.x - mean) * rstd * gv.x + bv.x),
                f2bf((v.y - mean) * rstd * gv.y + bv.y),
                f2bf((v.z - mean) * rstd * gv.z + bv.z),
                f2bf((v.w - mean) * rstd * gv.w + bv.w) };
  *reinterpret_cast<bf16x4*>(out + (size_t)row * 1024 + t * 4) = ov;
}

// ---------- weight transpose + f32->bf16 convert ----------
// 128k x 64n tile: 1KB-coalesced row reads, 64B/lane writes.
__global__ __launch_bounds__(256) void tcvt_k(const float* __restrict__ W,
                                              short* __restrict__ Wt,
                                              int N, size_t inStride, size_t outStride,
                                              int rowOff, int ldOut, float scale) {
  __shared__ float T[128][68];
  const float* Win = W + blockIdx.z * inStride;
  short* Wout = Wt + blockIdx.z * outStride;
  const int n0 = blockIdx.x * 64, k0 = blockIdx.y * 128;
  const int t = threadIdx.x;
  const int nc = (t & 15) * 4, kr = t >> 4;
#pragma unroll
  for (int p = 0; p < 8; ++p) {
    const float4 v = *reinterpret_cast<const float4*>(Win + (size_t)(k0 + kr + 16 * p) * N + n0 + nc);
    T[kr + 16 * p][nc + 0] = v.x;
    T[kr + 16 * p][nc + 1] = v.y;
    T[kr + 16 * p][nc + 2] = v.z;
    T[kr + 16 * p][nc + 3] = v.w;
  }
  __syncthreads();
  const int n = t >> 2, ks = (t & 3) * 32;
  short tmp[32];
#pragma unroll
  for (int i = 0; i < 32; ++i) tmp[i] = f2bf(T[ks + i][n] * scale);
  short* op = Wout + (size_t)(rowOff + n0 + n) * ldOut + k0 + ks;
#pragma unroll
  for (int c = 0; c < 4; ++c)
    *reinterpret_cast<bf16x8*>(op + c * 8) = *reinterpret_cast<bf16x8*>(tmp + c * 8);
}

// concat qkv bias (q scaled by 0.125)
__global__ __launch_bounds__(256) void bqkv_k(const float* __restrict__ qb,
                                              const float* __restrict__ kb,
                                              const float* __restrict__ vb,
                                              float* __restrict__ o) {
  int l = blockIdx.y;
  int c = blockIdx.x * 256 + threadIdx.x;
  float v;
  if (c < 1024) v = qb[l * 1024 + c] * 0.125f;
  else if (c < 1280) v = kb[l * 256 + c - 1024];
  else v = vb[l * 256 + c - 1280];
  o[l * 1536 + c] = v;
}

// ---------- V transpose (fallback path only) ----------
__global__ __launch_bounds__(256) void vtr_k(const short* __restrict__ v, int vld,
                                             short* __restrict__ vt) {
  __shared__ short T[64][80];
  const int kvh = blockIdx.y;
  const int s0 = blockIdx.x * 64;
  const int t = threadIdx.x;
  const int row = t >> 3, ch = t & 7;
#pragma unroll
  for (int p = 0; p < 2; ++p) {
    int s = row + 32 * p;
    bf16x8 vv = *reinterpret_cast<const bf16x8*>(v + (size_t)(s0 + s) * vld + kvh * 64 + ch * 8);
    *reinterpret_cast<bf16x8*>(&T[s][ch * 8]) = vv;
  }
  __syncthreads();
#pragma unroll
  for (int p = 0; p < 2; ++p) {
    int d = row + 32 * p;
    short tmp[8];
#pragma unroll
    for (int i = 0; i < 8; ++i) tmp[i] = T[ch * 8 + i][d];
    *reinterpret_cast<bf16x8*>(vt + (size_t)(kvh * 64 + d) * 2048 + s0 + ch * 8) =
        *reinterpret_cast<bf16x8*>(tmp);
  }
}

// ---------- GEMM (m97 structure): C[M,N] = A_bf16[M,K] @ Wt_bf16[N,K]^T ----------
// EPI: 0 bf16 out (acc+bias); 1 bf16 GELU(acc+bias); 2 f32 resid+acc+bias;
//      3 f32 acc; 4 = EPI0 + transposed-V scatter (cols>=1280 -> vt[(col-1280)][row])
// XSWZ: 0 identity; 1 m-fastest bijective XCD chunking (L2 W-panel reuse)
// TILE: 0 = 128x128 (16 MFMA x2 per K-step); 1 = 128x64 (2x the blocks, for N<=1536 GEMMs)
template <int EPI, int XSWZ, int TILE>
__global__ __launch_bounds__(256, 4)
void gemm_bt(const short* __restrict__ A, const short* __restrict__ Wt,
             const float* __restrict__ bias, const float* __restrict__ resid,
             void* __restrict__ out, int M, int N, int K, int nbOff,
             short* __restrict__ vt) {
  constexpr int BN   = (TILE == 0) ? 128 : 64;  // block n-extent
  constexpr int WN   = (TILE == 0) ? 64 : 32;   // wave n-extent
  constexpr int NT   = (TILE == 0) ? 4 : 2;     // n-frags per wave
  constexpr int BISS = (TILE == 0) ? 4 : 2;     // B staging issues per wave
  __shared__ short As[128 * 64];
  __shared__ short Bs[BN * 64];
  const int t = threadIdx.x;
  const int lane = t & 63, w = t >> 6;
  const int g = lane >> 4, r = lane & 15;
  const int wr = w >> 1, wc = w & 1;

  int bx = blockIdx.x, by = blockIdx.y;
  if (XSWZ == 1) {
    const int nbx = gridDim.x, nby = gridDim.y, nwg = nbx * nby;
    const int bid = by * nbx + bx;
    const int q = nwg >> 3, rr = nwg & 7;
    const int xcd = bid & 7, loc = bid >> 3;
    const int sw = (xcd < rr ? xcd * (q + 1) : rr * (q + 1) + (xcd - rr) * q) + loc;
    by = sw % nby; bx = sw / nby;  // m-fastest: XCD-contiguous blocks share an n-panel
  }
  const int m0 = by * 128, n0 = (bx + nbOff) * BN;

  f32x4 acc[4][NT];
#pragma unroll
  for (int i = 0; i < 4; ++i)
#pragma unroll
    for (int j = 0; j < NT; ++j) { f32x4 z = {0.f, 0.f, 0.f, 0.f}; acc[i][j] = z; }

  const int srow = lane >> 3, sslot = lane & 7;

  for (int k0 = 0; k0 < K; k0 += 64) {
#pragma unroll
    for (int i = 0; i < 4; ++i) {
      const int rowA = w * 32 + i * 8 + srow;
      const int colA = (sslot ^ (srow & 7)) << 3;
      gload16(A + (size_t)(m0 + rowA) * K + k0 + colA, &As[(w * 32 + i * 8) * 64]);
    }
#pragma unroll
    for (int i = 0; i < BISS; ++i) {
      const int rowB = w * (8 * BISS) + i * 8 + srow;
      const int colB = (sslot ^ (srow & 7)) << 3;
      gload16(Wt + (size_t)(n0 + rowB) * K + k0 + colB, &Bs[(w * (8 * BISS) + i * 8) * 64]);
    }
    __syncthreads();
#pragma unroll
    for (int kk = 0; kk < 64; kk += 32) {
      bf16x8 af[4], bfg[NT];
#pragma unroll
      for (int mt = 0; mt < 4; ++mt)
        af[mt] = *reinterpret_cast<const bf16x8*>(&As[swz(wr * 64 + mt * 16 + r, kk + g * 8)]);
#pragma unroll
      for (int nt = 0; nt < NT; ++nt)
        bfg[nt] = *reinterpret_cast<const bf16x8*>(&Bs[swz(wc * WN + nt * 16 + r, kk + g * 8)]);
#pragma unroll
      for (int mt = 0; mt < 4; ++mt)
#pragma unroll
        for (int nt = 0; nt < NT; ++nt)
          acc[mt][nt] = mfma16(af[mt], bfg[nt], acc[mt][nt]);
    }
    __syncthreads();
  }
#pragma unroll
  for (int nt = 0; nt < NT; ++nt) {
    const int col = n0 + wc * WN + nt * 16 + r;
    const float bv = (EPI == 3) ? 0.f : bias[col];
#pragma unroll
    for (int mt = 0; mt < 4; ++mt) {
#pragma unroll
      for (int j = 0; j < 4; ++j) {
        const int row = m0 + wr * 64 + mt * 16 + 4 * g + j;
        const size_t oi = (size_t)row * N + col;
        float vv = acc[mt][nt][j] + bv;
        if (EPI == 0) {
          ((short*)out)[oi] = f2bf(vv);
        } else if (EPI == 1) {
          vv = 0.5f * vv * (1.f + erff(vv * 0.70710678118654752f));
          ((short*)out)[oi] = f2bf(vv);
        } else if (EPI == 2) {
          ((float*)out)[oi] = resid[oi] + vv;
        } else if (EPI == 3) {
          ((float*)out)[oi] = vv;
        } else {  // EPI 4
          short bb = f2bf(vv);
          ((short*)out)[oi] = bb;
          if (col >= 1280) vt[(size_t)(col - 1280) * 2048 + row] = bb;
        }
      }
    }
  }
}

// ---------- legacy GEMM (f32 weights) — fallback if ws too small ----------
template <int EPI>
__global__ __launch_bounds__(256)
void gemm_k(const short* __restrict__ A, const float* __restrict__ W,
            const float* __restrict__ bias, const float* resid, void* out,
            int M, int N, int K, float scale) {
  __shared__ short As[128 * 64];
  __shared__ short Bs[128 * 64];
  const int t = threadIdx.x;
  const int lane = t & 63;
  const int g = lane >> 4, r = lane & 15;
  const int wid = t >> 6, wr = wid >> 1, wc = wid & 1;
  const int m0 = blockIdx.y * 128, n0 = blockIdx.x * 128;
  f32x4 acc[4][4];
#pragma unroll
  for (int i = 0; i < 4; ++i)
#pragma unroll
    for (int j = 0; j < 4; ++j) { f32x4 z = {0.f, 0.f, 0.f, 0.f}; acc[i][j] = z; }
  const int arow = t >> 3, ac = t & 7;
  const int bnn = t >> 1, bkh = t & 1;
  for (int k0 = 0; k0 < K; k0 += 64) {
#pragma unroll
    for (int p = 0; p < 4; ++p) {
      int row = arow + 32 * p;
      bf16x8 av = *reinterpret_cast<const bf16x8*>(A + (size_t)(m0 + row) * K + k0 + ac * 8);
      *reinterpret_cast<bf16x8*>(&As[swz(row, ac * 8)]) = av;
    }
#pragma unroll
    for (int p = 0; p < 8; ++p) {
      int kg = 4 * (bkh + 2 * p);
      const float* wp = W + (size_t)(k0 + kg) * N + n0 + bnn;
      bf16x4 wv = { f2bf(wp[0]), f2bf(wp[(size_t)N]), f2bf(wp[(size_t)2 * N]), f2bf(wp[(size_t)3 * N]) };
      *reinterpret_cast<bf16x4*>(&Bs[swz(bnn, kg)]) = wv;
    }
    __syncthreads();
#pragma unroll
    for (int kk = 0; kk < 64; kk += 32) {
      bf16x8 af[4], bfg[4];
#pragma unroll
      for (int mt = 0; mt < 4; ++mt)
        af[mt] = *reinterpret_cast<const bf16x8*>(&As[swz(wr * 64 + mt * 16 + r, kk + g * 8)]);
#pragma unroll
      for (int nt = 0; nt < 4; ++nt)
        bfg[nt] = *reinterpret_cast<const bf16x8*>(&Bs[swz(wc * 64 + nt * 16 + r, kk + g * 8)]);
#pragma unroll
      for (int mt = 0; mt < 4; ++mt)
#pragma unroll
        for (int nt = 0; nt < 4; ++nt)
          acc[mt][nt] = mfma16(af[mt], bfg[nt], acc[mt][nt]);
    }
    __syncthreads();
  }
#pragma unroll
  for (int nt = 0; nt < 4; ++nt) {
    const int col = n0 + wc * 64 + nt * 16 + r;
    const float bv = (EPI == 3) ? 0.f : bias[col];
#pragma unroll
    for (int mt = 0; mt < 4; ++mt) {
#pragma unroll
      for (int j = 0; j < 4; ++j) {
        const int row = m0 + wr * 64 + mt * 16 + 4 * g + j;
        const size_t oi = (size_t)row * N + col;
        float vv = acc[mt][nt][j] + bv;
        if (EPI == 0) {
          ((short*)out)[oi] = f2bf(vv * scale);
        } else if (EPI == 1) {
          vv = 0.5f * vv * (1.f + erff(vv * 0.70710678118654752f));
          ((short*)out)[oi] = f2bf(vv);
        } else if (EPI == 2) {
          ((float*)out)[oi] = resid[oi] + vv;
        } else {
          ((float*)out)[oi] = vv;
        }
      }
    }
  }
}

// ---------- flash-style GQA attention (dbuf, gload_lds staging) ----------
__global__ __launch_bounds__(256) void attn_k(const short* __restrict__ q, int qld,
                                              const short* __restrict__ k, int kld,
                                              const short* __restrict__ vt,
                                              const float* __restrict__ mask,
                                              short* __restrict__ o) {
  __shared__ short Ks[2][64 * 64];  // [s][d], 16B-chunk swizzled
  __shared__ short Vs[2][64 * 64];  // [d][s], 16B-chunk swizzled
  const int t = threadIdx.x, lane = t & 63, w = t >> 6;
  const int g = lane >> 4, r = lane & 15;
  const int h = blockIdx.y, qb = blockIdx.x, kvh = h >> 2;
  const int qrow = qb * 64 + w * 16 + r;

  const short* qp = q + (size_t)qrow * qld + h * 64;
  bf16x8 qf0 = *reinterpret_cast<const bf16x8*>(qp + g * 8);
  bf16x8 qf1 = *reinterpret_cast<const bf16x8*>(qp + 32 + g * 8);

  const short* kbase = k + kvh * 64;                   // + s*kld
  const short* vbase = vt + (size_t)kvh * 64 * 2048;   // + d*2048 + s

  f32x4 oacc[4];
#pragma unroll
  for (int i = 0; i < 4; ++i) { f32x4 z = {0.f, 0.f, 0.f, 0.f}; oacc[i] = z; }
  float m_run = -INFINITY, l_run = 0.f;

  const int srow = w * 8 + (lane >> 3), schunk = lane & 7;

#pragma unroll
  for (int p = 0; p < 2; ++p) {
    const int rr = srow + 32 * p;
    const int cc = (schunk ^ (rr & 7)) << 3;
    gload16(kbase + (size_t)rr * kld + cc, (char*)Ks + p * 4096 + w * 1024);
    gload16(vbase + (size_t)rr * 2048 + cc, (char*)Vs + p * 4096 + w * 1024);
  }
  asm volatile("s_waitcnt vmcnt(0)" ::: "memory");
  __syncthreads();

  for (int it = 0; it < 32; ++it) {
    const int cur = it & 1;
    if (it < 31) {
      const int s1 = (it + 1) * 64;
#pragma unroll
      for (int p = 0; p < 2; ++p) {
        const int rr = srow + 32 * p;
        const int cc = (schunk ^ (rr & 7)) << 3;
        gload16(kbase + (size_t)(s1 + rr) * kld + cc,
                (char*)Ks + (cur ^ 1) * 8192 + p * 4096 + w * 1024);
        gload16(vbase + (size_t)rr * 2048 + s1 + cc,
                (char*)Vs + (cur ^ 1) * 8192 + p * 4096 + w * 1024);
      }
    }
    const int s0 = it * 64;
    const short* Kc = Ks[cur];
    const short* Vc = Vs[cur];

    f32x4 sa[4];
#pragma unroll
    for (int st = 0; st < 4; ++st) {
      bf16x8 kf0 = *reinterpret_cast<const bf16x8*>(&Kc[swz(st * 16 + r, g * 8)]);
      bf16x8 kf1 = *reinterpret_cast<const bf16x8*>(&Kc[swz(st * 16 + r, 32 + g * 8)]);
      f32x4 z = {0.f, 0.f, 0.f, 0.f};
      z = mfma16(kf0, qf0, z);
      z = mfma16(kf1, qf1, z);
      sa[st] = z;
    }
    float sv[16];
    float pmax = -INFINITY;
#pragma unroll
    for (int st = 0; st < 4; ++st) {
      const float4 mv = *reinterpret_cast<const float4*>(mask + s0 + st * 16 + 4 * g);
#pragma unroll
      for (int j = 0; j < 4; ++j) {
        float xx = sa[st][j] + ((const float*)&mv)[j];
        sv[st * 4 + j] = xx;
        pmax = fmaxf(pmax, xx);
      }
    }
    pmax = fmaxf(pmax, __shfl_xor(pmax, 16));
    pmax = fmaxf(pmax, __shfl_xor(pmax, 32));
    float m_new = fmaxf(m_run, pmax);
    float corr = __expf(m_run - m_new);
    float psum = 0.f;
    short pb[16];
#pragma unroll
    for (int i = 0; i < 16; ++i) {
      float p = __expf(sv[i] - m_new);
      psum += p;
      pb[i] = f2bf(p);
    }
    psum += __shfl_xor(psum, 16);
    psum += __shfl_xor(psum, 32);
    l_run = l_run * corr + psum;
    m_run = m_new;
#pragma unroll
    for (int dt = 0; dt < 4; ++dt)
#pragma unroll
      for (int j = 0; j < 4; ++j) oacc[dt][j] *= corr;

#pragma unroll
    for (int hs = 0; hs < 2; ++hs) {
      bf16x8 pf = { pb[hs * 8 + 0], pb[hs * 8 + 1], pb[hs * 8 + 2], pb[hs * 8 + 3],
                    pb[hs * 8 + 4], pb[hs * 8 + 5], pb[hs * 8 + 6], pb[hs * 8 + 7] };
#pragma unroll
      for (int dt = 0; dt < 4; ++dt) {
        int d = dt * 16 + r;
        int c1 = 4 * g + 32 * hs;
        bf16x4 va  = *reinterpret_cast<const bf16x4*>(&Vc[swz(d, c1)]);
        bf16x4 vb2 = *reinterpret_cast<const bf16x4*>(&Vc[swz(d, c1 + 16)]);
        bf16x8 vf = { va[0], va[1], va[2], va[3], vb2[0], vb2[1], vb2[2], vb2[3] };
        oacc[dt] = mfma16(vf, pf, oacc[dt]);
      }
    }
    asm volatile("s_waitcnt vmcnt(0)" ::: "memory");
    __syncthreads();
  }
  float inv = 1.f / l_run;
#pragma unroll
  for (int dt = 0; dt < 4; ++dt) {
    bf16x4 ov = { f2bf(oacc[dt][0] * inv), f2bf(oacc[dt][1] * inv),
                  f2bf(oacc[dt][2] * inv), f2bf(oacc[dt][3] * inv) };
    *reinterpret_cast<bf16x4*>(o + (size_t)qrow * 1024 + h * 64 + dt * 16 + 4 * g) = ov;
  }
}

// ---------- launch ----------
extern "C" void kernel_launch(void* const* d_in, const int* in_sizes, int n_in,
                              void* d_out, int out_size, void* d_ws, size_t ws_size,
                              hipStream_t stream) {
  const int*   ids   = (const int*)d_in[0];
  const float* mask  = (const float*)d_in[1];
  const float* tok   = (const float*)d_in[2];
  const float* pos   = (const float*)d_in[3];
  const float* qW    = (const float*)d_in[4];
  const float* qbias = (const float*)d_in[5];
  const float* kW    = (const float*)d_in[6];
  const float* kbias = (const float*)d_in[7];
  const float* vW    = (const float*)d_in[8];
  const float* vbias = (const float*)d_in[9];
  const float* oW    = (const float*)d_in[10];
  const float* obias = (const float*)d_in[11];
  const float* m1W   = (const float*)d_in[12];
  const float* m1b   = (const float*)d_in[13];
  const float* m2W   = (const float*)d_in[14];
  const float* m2b   = (const float*)d_in[15];
  const float* ln1g  = (const float*)d_in[16];
  const float* ln1b  = (const float*)d_in[17];
  const float* ln2g  = (const float*)d_in[18];
  const float* ln2b  = (const float*)d_in[19];
  const float* lnfg  = (const float*)d_in[20];
  const float* lnfb  = (const float*)d_in[21];
  const float* headW = (const float*)d_in[22];
  float* out = (float*)d_out;

  char* ws = (char*)d_ws;
  float* x   = (float*)ws;                        // 8 MB
  short* xb  = (short*)(ws + 8388608ull);         // 4 MB

  const size_t OFF_QKV  = 12582912ull;   // 6 MB  bf16 [2048][1536]
  const size_t OFF_AO   = 18874368ull;   // 4 MB
  const size_t OFF_FF   = 23068672ull;   // 16 MB (first 1 MB aliased as vt between QKV-GEMM and attn)
  const size_t OFF_BQ   = 39845888ull;   // 24 KB f32 [4][1536]
  const size_t OFF_WQKV = 39870464ull;   // 12 MB bf16 [4][1536][1024]
  const size_t OFF_WO   = 52453376ull;   // 8 MB  bf16 [4][1024][1024]
  const size_t OFF_WM1  = 60841984ull;   // 32 MB bf16 [4][4096][1024]
  const size_t OFF_WM2  = 94396416ull;   // 32 MB bf16 [4][1024][4096]
  const size_t OFF_WH   = 127950848ull;  // 64 MB bf16 [32000][1024]
  const size_t NEED     = 193486848ull;

  if (ws_size >= NEED) {
    short* qkv  = (short*)(ws + OFF_QKV);
    short* ao   = (short*)(ws + OFF_AO);
    short* ff   = (short*)(ws + OFF_FF);
    short* vt   = ff;  // alias: ff dead during QKV->attn window
    float* bqv  = (float*)(ws + OFF_BQ);
    short* Wqkv = (short*)(ws + OFF_WQKV);
    short* Wo   = (short*)(ws + OFF_WO);
    short* Wm1  = (short*)(ws + OFF_WM1);
    short* Wm2  = (short*)(ws + OFF_WM2);
    short* Wh   = (short*)(ws + OFF_WH);

    tcvt_k<<<dim3(16, 8, 4), 256, 0, stream>>>(qW, Wqkv, 1024, 1048576ull, 1572864ull, 0, 1024, 0.125f);
    tcvt_k<<<dim3(4, 8, 4),  256, 0, stream>>>(kW, Wqkv, 256,  262144ull,  1572864ull, 1024, 1024, 1.f);
    tcvt_k<<<dim3(4, 8, 4),  256, 0, stream>>>(vW, Wqkv, 256,  262144ull,  1572864ull, 1280, 1024, 1.f);
    tcvt_k<<<dim3(16, 8, 4), 256, 0, stream>>>(oW, Wo, 1024, 1048576ull, 1048576ull, 0, 1024, 1.f);
    tcvt_k<<<dim3(64, 8, 4), 256, 0, stream>>>(m1W, Wm1, 4096, 4194304ull, 4194304ull, 0, 1024, 1.f);
    tcvt_k<<<dim3(16, 32, 4), 256, 0, stream>>>(m2W, Wm2, 1024, 4194304ull, 4194304ull, 0, 4096, 1.f);
    tcvt_k<<<dim3(500, 8, 1), 256, 0, stream>>>(headW, Wh, 32000, 0ull, 0ull, 0, 1024, 1.f);
    bqkv_k<<<dim3(6, 4), 256, 0, stream>>>(qbias, kbias, vbias, bqv);

    embed_k<<<2048, 256, 0, stream>>>(ids, tok, pos, x);

    for (int l = 0; l < 4; ++l) {
      short* Wq_l  = Wqkv + (size_t)l * 1536 * 1024;
      short* Wo_l  = Wo   + (size_t)l * 1024 * 1024;
      short* Wm1_l = Wm1  + (size_t)l * 4096 * 1024;
      short* Wm2_l = Wm2  + (size_t)l * 1024 * 4096;

      ln_k<<<2048, 256, 0, stream>>>(x, ln1g + l * 1024, ln1b + l * 1024, xb);
      gemm_bt<4, 0, 1><<<dim3(24, 16), 256, 0, stream>>>(xb, Wq_l, bqv + l * 1536, nullptr,
                                                         qkv, 2048, 1536, 1024, 0, vt);
      attn_k<<<dim3(32, 16), 256, 0, stream>>>(qkv, 1536, qkv + 1024, 1536, vt, mask, ao);
      gemm_bt<2, 0, 1><<<dim3(16, 16), 256, 0, stream>>>(ao, Wo_l, obias + l * 1024, x,
                                                         x, 2048, 1024, 1024, 0, nullptr);
      ln_k<<<2048, 256, 0, stream>>>(x, ln2g + l * 1024, ln2b + l * 1024, xb);
      gemm_bt<1, 1, 0><<<dim3(32, 16), 256, 0, stream>>>(xb, Wm1_l, m1b + l * 4096, nullptr,
                                                         ff, 2048, 4096, 1024, 0, nullptr);
      gemm_bt<2, 1, 1><<<dim3(16, 16), 256, 0, stream>>>(ff, Wm2_l, m2b + l * 1024, x,
                                                         x, 2048, 1024, 4096, 0, nullptr);
    }
    ln_k<<<2048, 256, 0, stream>>>(x, lnfg, lnfb, xb);
    gemm_bt<3, 1, 0><<<dim3(250, 16), 256, 0, stream>>>(xb, Wh, nullptr, nullptr,
                                                        out, 2048, 32000, 1024, 0, nullptr);
  } else {
    // fallback: f32-weight GEMMs, needs < 40 MB ws
    short* qbf = (short*)(ws + (12u << 20));
    short* kbf = (short*)(ws + (16u << 20));
    short* vbf = (short*)(ws + (17u << 20));
    short* ao  = (short*)(ws + (18u << 20));
    short* ff  = (short*)(ws + (22u << 20));
    short* vtf = (short*)(ws + (38u << 20));

    embed_k<<<2048, 256, 0, stream>>>(ids, tok, pos, x);
    for (int l = 0; l < 4; ++l) {
      ln_k<<<2048, 256, 0, stream>>>(x, ln1g + l * 1024, ln1b + l * 1024, xb);
      gemm_k<0><<<dim3(8, 16), 256, 0, stream>>>(xb, qW + (size_t)l * 1024 * 1024,
          qbias + l * 1024, nullptr, qbf, 2048, 1024, 1024, 0.125f);
      gemm_k<0><<<dim3(2, 16), 256, 0, stream>>>(xb, kW + (size_t)l * 1024 * 256,
          kbias + l * 256, nullptr, kbf, 2048, 256, 1024, 1.f);
      gemm_k<0><<<dim3(2, 16), 256, 0, stream>>>(xb, vW + (size_t)l * 1024 * 256,
          vbias + l * 256, nullptr, vbf, 2048, 256, 1024, 1.f);
      vtr_k<<<dim3(32, 4), 256, 0, stream>>>(vbf, 256, vtf);
      attn_k<<<dim3(32, 16), 256, 0, stream>>>(qbf, 1024, kbf, 256, vtf, mask, ao);
      gemm_k<2><<<dim3(8, 16), 256, 0, stream>>>(ao, oW + (size_t)l * 1024 * 1024,
          obias + l * 1024, x, x, 2048, 1024, 1024, 1.f);
      ln_k<<<2048, 256, 0, stream>>>(x, ln2g + l * 1024, ln2b + l * 1024, xb);
      gemm_k<1><<<dim3(32, 16), 256, 0, stream>>>(xb, m1W + (size_t)l * 1024 * 4096,
          m1b + l * 4096, nullptr, ff, 2048, 4096, 1024, 1.f);
      gemm_k<2><<<dim3(8, 16), 256, 0, stream>>>(ff, m2W + (size_t)l * 4096 * 1024,
          m2b + l * 1024, x, x, 2048, 1024, 4096, 1.f);
    }
    ln_k<<<2048, 256, 0, stream>>>(x, lnfg, lnfb, xb);
    gemm_k<3><<<dim3(250, 16), 256, 0, stream>>>(xb, headW, nullptr, nullptr, out,
        2048, 32000, 1024, 1.f);
  }
}

// Round 6
// 1175.936 us; speedup vs baseline: 3.6093x; 1.0132x over previous
//
#include <hip/hip_runtime.h>
#include <stdint.h>
#include <math.h>

// ---------- types ----------
typedef __attribute__((ext_vector_type(8))) short bf16x8;   // 8 bf16 (4 VGPR)
typedef __attribute__((ext_vector_type(4))) short bf16x4;
typedef __attribute__((ext_vector_type(4))) float f32x4;

__device__ __forceinline__ short f2bf(float f) {
  unsigned u = __builtin_bit_cast(unsigned, f);
  unsigned r = u + 0x7fffu + ((u >> 16) & 1u);
  return (short)(r >> 16);
}

__device__ __forceinline__ f32x4 mfma16(bf16x8 a, bf16x8 b, f32x4 c) {
  return __builtin_amdgcn_mfma_f32_16x16x32_bf16(a, b, c, 0, 0, 0);
}

// async global->LDS, 16B per lane. LDS dest = wave-uniform base + lane*16.
__device__ __forceinline__ void gload16(const void* g, void* l) {
  __builtin_amdgcn_global_load_lds((const __attribute__((address_space(1))) void*)g,
                                   (__attribute__((address_space(3))) void*)l, 16, 0, 0);
}

// LDS tile index: row-major [rows][64] bf16, 16B-chunk XOR swizzle on row&7.
__device__ __forceinline__ int swz(int row, int col) {
  return row * 64 + (((col >> 3) ^ (row & 7)) << 3) + (col & 7);
}

// ---------- embedding (4 rows/block, wave per row) ----------
__global__ __launch_bounds__(256) void embed_k(const int* __restrict__ ids,
                                               const float* __restrict__ tok,
                                               const float* __restrict__ pos,
                                               float* __restrict__ x) {
  const int t = threadIdx.x, w = t >> 6, lane = t & 63;
  const int row = blockIdx.x * 4 + w;
  const int id = ids[row];
#pragma unroll
  for (int i = 0; i < 4; ++i) {
    const int c = (i * 64 + lane) * 4;
    const float4 a = *reinterpret_cast<const float4*>(tok + (size_t)id * 1024 + c);
    const float4 b = *reinterpret_cast<const float4*>(pos + (size_t)row * 1024 + c);
    float4 o = make_float4(a.x + b.x, a.y + b.y, a.z + b.z, a.w + b.w);
    *reinterpret_cast<float4*>(x + (size_t)row * 1024 + c) = o;
  }
}

// ---------- layernorm (wave per row, 4 rows/block, no LDS/barrier) ----------
__global__ __launch_bounds__(256) void ln_k(const float* __restrict__ x,
                                            const float* __restrict__ gw,
                                            const float* __restrict__ bw,
                                            short* __restrict__ out) {
  const int t = threadIdx.x, w = t >> 6, lane = t & 63;
  const int row = blockIdx.x * 4 + w;
  float4 v[4];
  float s = 0.f, q = 0.f;
#pragma unroll
  for (int i = 0; i < 4; ++i) {
    v[i] = *reinterpret_cast<const float4*>(x + (size_t)row * 1024 + (i * 64 + lane) * 4);
    s += v[i].x + v[i].y + v[i].z + v[i].w;
    q += v[i].x * v[i].x + v[i].y * v[i].y + v[i].z * v[i].z + v[i].w * v[i].w;
  }
#pragma unroll
  for (int o = 32; o > 0; o >>= 1) { s += __shfl_xor(s, o); q += __shfl_xor(q, o); }
  const float mean = s * (1.f / 1024.f);
  const float var  = q * (1.f / 1024.f) - mean * mean;
  const float rstd = rsqrtf(var + 1e-5f);
#pragma unroll
  for (int i = 0; i < 4; ++i) {
    const int c = (i * 64 + lane) * 4;
    const float4 gv = *reinterpret_cast<const float4*>(gw + c);
    const float4 bv = *reinterpret_cast<const float4*>(bw + c);
    bf16x4 ov = { f2bf((v[i].x - mean) * rstd * gv.x + bv.x),
                  f2bf((v[i].y - mean) * rstd * gv.y + bv.y),
                  f2bf((v[i].z - mean) * rstd * gv.z + bv.z),
                  f2bf((v[i].w - mean) * rstd * gv.w + bv.w) };
    *reinterpret_cast<bf16x4*>(out + (size_t)row * 1024 + c) = ov;
  }
}

// ---------- weight transpose + f32->bf16 convert ----------
// 128k x 64n tile: 1KB-coalesced row reads, 64B/lane writes.
__global__ __launch_bounds__(256) void tcvt_k(const float* __restrict__ W,
                                              short* __restrict__ Wt,
                                              int N, size_t inStride, size_t outStride,
                                              int rowOff, int ldOut, float scale) {
  __shared__ float T[128][68];
  const float* Win = W + blockIdx.z * inStride;
  short* Wout = Wt + blockIdx.z * outStride;
  const int n0 = blockIdx.x * 64, k0 = blockIdx.y * 128;
  const int t = threadIdx.x;
  const int nc = (t & 15) * 4, kr = t >> 4;
#pragma unroll
  for (int p = 0; p < 8; ++p) {
    const float4 v = *reinterpret_cast<const float4*>(Win + (size_t)(k0 + kr + 16 * p) * N + n0 + nc);
    T[kr + 16 * p][nc + 0] = v.x;
    T[kr + 16 * p][nc + 1] = v.y;
    T[kr + 16 * p][nc + 2] = v.z;
    T[kr + 16 * p][nc + 3] = v.w;
  }
  __syncthreads();
  const int n = t >> 2, ks = (t & 3) * 32;
  short tmp[32];
#pragma unroll
  for (int i = 0; i < 32; ++i) tmp[i] = f2bf(T[ks + i][n] * scale);
  short* op = Wout + (size_t)(rowOff + n0 + n) * ldOut + k0 + ks;
#pragma unroll
  for (int c = 0; c < 4; ++c)
    *reinterpret_cast<bf16x8*>(op + c * 8) = *reinterpret_cast<bf16x8*>(tmp + c * 8);
}

// concat qkv bias (q scaled by 0.125)
__global__ __launch_bounds__(256) void bqkv_k(const float* __restrict__ qb,
                                              const float* __restrict__ kb,
                                              const float* __restrict__ vb,
                                              float* __restrict__ o) {
  int l = blockIdx.y;
  int c = blockIdx.x * 256 + threadIdx.x;
  float v;
  if (c < 1024) v = qb[l * 1024 + c] * 0.125f;
  else if (c < 1280) v = kb[l * 256 + c - 1024];
  else v = vb[l * 256 + c - 1280];
  o[l * 1536 + c] = v;
}

// ---------- V transpose (fallback path only) ----------
__global__ __launch_bounds__(256) void vtr_k(const short* __restrict__ v, int vld,
                                             short* __restrict__ vt) {
  __shared__ short T[64][80];
  const int kvh = blockIdx.y;
  const int s0 = blockIdx.x * 64;
  const int t = threadIdx.x;
  const int row = t >> 3, ch = t & 7;
#pragma unroll
  for (int p = 0; p < 2; ++p) {
    int s = row + 32 * p;
    bf16x8 vv = *reinterpret_cast<const bf16x8*>(v + (size_t)(s0 + s) * vld + kvh * 64 + ch * 8);
    *reinterpret_cast<bf16x8*>(&T[s][ch * 8]) = vv;
  }
  __syncthreads();
#pragma unroll
  for (int p = 0; p < 2; ++p) {
    int d = row + 32 * p;
    short tmp[8];
#pragma unroll
    for (int i = 0; i < 8; ++i) tmp[i] = T[ch * 8 + i][d];
    *reinterpret_cast<bf16x8*>(vt + (size_t)(kvh * 64 + d) * 2048 + s0 + ch * 8) =
        *reinterpret_cast<bf16x8*>(tmp);
  }
}

// ---------- GEMM (m97 structure): C[M,N] = A_bf16[M,K] @ Wt_bf16[N,K]^T ----------
// EPI: 0 bf16 out (acc+bias); 1 bf16 GELU(acc+bias); 2 f32 resid+acc+bias;
//      3 f32 acc; 4 = EPI0 + transposed-V store (cols>=1280 -> vt[(col-1280)][row], bf16x4)
// XSWZ: 0 identity; 1 m-fastest bijective XCD chunking (L2 W-panel reuse)
// TILE: 0 = 128x128; 1 = 128x64 (2x blocks, for N<=1536 or latency-bound GEMMs)
template <int EPI, int XSWZ, int TILE>
__global__ __launch_bounds__(256, 4)
void gemm_bt(const short* __restrict__ A, const short* __restrict__ Wt,
             const float* __restrict__ bias, const float* __restrict__ resid,
             void* __restrict__ out, int M, int N, int K, int nbOff,
             short* __restrict__ vt) {
  constexpr int BN   = (TILE == 0) ? 128 : 64;  // block n-extent
  constexpr int WN   = (TILE == 0) ? 64 : 32;   // wave n-extent
  constexpr int NT   = (TILE == 0) ? 4 : 2;     // n-frags per wave
  constexpr int BISS = (TILE == 0) ? 4 : 2;     // B staging issues per wave
  __shared__ short As[128 * 64];
  __shared__ short Bs[BN * 64];
  const int t = threadIdx.x;
  const int lane = t & 63, w = t >> 6;
  const int g = lane >> 4, r = lane & 15;
  const int wr = w >> 1, wc = w & 1;

  int bx = blockIdx.x, by = blockIdx.y;
  if (XSWZ == 1) {
    const int nbx = gridDim.x, nby = gridDim.y, nwg = nbx * nby;
    const int bid = by * nbx + bx;
    const int q = nwg >> 3, rr = nwg & 7;
    const int xcd = bid & 7, loc = bid >> 3;
    const int sw = (xcd < rr ? xcd * (q + 1) : rr * (q + 1) + (xcd - rr) * q) + loc;
    by = sw % nby; bx = sw / nby;  // m-fastest: XCD-contiguous blocks share an n-panel
  }
  const int m0 = by * 128, n0 = (bx + nbOff) * BN;

  f32x4 acc[4][NT];
#pragma unroll
  for (int i = 0; i < 4; ++i)
#pragma unroll
    for (int j = 0; j < NT; ++j) { f32x4 z = {0.f, 0.f, 0.f, 0.f}; acc[i][j] = z; }

  const int srow = lane >> 3, sslot = lane & 7;

  for (int k0 = 0; k0 < K; k0 += 64) {
#pragma unroll
    for (int i = 0; i < 4; ++i) {
      const int rowA = w * 32 + i * 8 + srow;
      const int colA = (sslot ^ (srow & 7)) << 3;
      gload16(A + (size_t)(m0 + rowA) * K + k0 + colA, &As[(w * 32 + i * 8) * 64]);
    }
#pragma unroll
    for (int i = 0; i < BISS; ++i) {
      const int rowB = w * (8 * BISS) + i * 8 + srow;
      const int colB = (sslot ^ (srow & 7)) << 3;
      gload16(Wt + (size_t)(n0 + rowB) * K + k0 + colB, &Bs[(w * (8 * BISS) + i * 8) * 64]);
    }
    __syncthreads();
#pragma unroll
    for (int kk = 0; kk < 64; kk += 32) {
      bf16x8 af[4], bfg[NT];
#pragma unroll
      for (int mt = 0; mt < 4; ++mt)
        af[mt] = *reinterpret_cast<const bf16x8*>(&As[swz(wr * 64 + mt * 16 + r, kk + g * 8)]);
#pragma unroll
      for (int nt = 0; nt < NT; ++nt)
        bfg[nt] = *reinterpret_cast<const bf16x8*>(&Bs[swz(wc * WN + nt * 16 + r, kk + g * 8)]);
#pragma unroll
      for (int mt = 0; mt < 4; ++mt)
#pragma unroll
        for (int nt = 0; nt < NT; ++nt)
          acc[mt][nt] = mfma16(af[mt], bfg[nt], acc[mt][nt]);
    }
    __syncthreads();
  }
#pragma unroll
  for (int nt = 0; nt < NT; ++nt) {
    const int col = n0 + wc * WN + nt * 16 + r;
    const float bv = (EPI == 3) ? 0.f : bias[col];
#pragma unroll
    for (int mt = 0; mt < 4; ++mt) {
      const int rowb = m0 + wr * 64 + mt * 16 + 4 * g;
      short vs[4];
#pragma unroll
      for (int j = 0; j < 4; ++j) {
        const int row = rowb + j;
        const size_t oi = (size_t)row * N + col;
        float vv = acc[mt][nt][j] + bv;
        if (EPI == 0) {
          ((short*)out)[oi] = f2bf(vv);
        } else if (EPI == 1) {
          vv = 0.5f * vv * (1.f + erff(vv * 0.70710678118654752f));
          ((short*)out)[oi] = f2bf(vv);
        } else if (EPI == 2) {
          ((float*)out)[oi] = resid[oi] + vv;
        } else if (EPI == 3) {
          ((float*)out)[oi] = vv;
        } else {  // EPI 4
          short bb = f2bf(vv);
          ((short*)out)[oi] = bb;
          vs[j] = bb;
        }
      }
      if (EPI == 4 && col >= 1280) {
        bf16x4 pk = { vs[0], vs[1], vs[2], vs[3] };
        *reinterpret_cast<bf16x4*>(vt + (size_t)(col - 1280) * 2048 + rowb) = pk;
      }
    }
  }
}

// ---------- legacy GEMM (f32 weights) — fallback if ws too small ----------
template <int EPI>
__global__ __launch_bounds__(256)
void gemm_k(const short* __restrict__ A, const float* __restrict__ W,
            const float* __restrict__ bias, const float* resid, void* out,
            int M, int N, int K, float scale) {
  __shared__ short As[128 * 64];
  __shared__ short Bs[128 * 64];
  const int t = threadIdx.x;
  const int lane = t & 63;
  const int g = lane >> 4, r = lane & 15;
  const int wid = t >> 6, wr = wid >> 1, wc = wid & 1;
  const int m0 = blockIdx.y * 128, n0 = blockIdx.x * 128;
  f32x4 acc[4][4];
#pragma unroll
  for (int i = 0; i < 4; ++i)
#pragma unroll
    for (int j = 0; j < 4; ++j) { f32x4 z = {0.f, 0.f, 0.f, 0.f}; acc[i][j] = z; }
  const int arow = t >> 3, ac = t & 7;
  const int bnn = t >> 1, bkh = t & 1;
  for (int k0 = 0; k0 < K; k0 += 64) {
#pragma unroll
    for (int p = 0; p < 4; ++p) {
      int row = arow + 32 * p;
      bf16x8 av = *reinterpret_cast<const bf16x8*>(A + (size_t)(m0 + row) * K + k0 + ac * 8);
      *reinterpret_cast<bf16x8*>(&As[swz(row, ac * 8)]) = av;
    }
#pragma unroll
    for (int p = 0; p < 8; ++p) {
      int kg = 4 * (bkh + 2 * p);
      const float* wp = W + (size_t)(k0 + kg) * N + n0 + bnn;
      bf16x4 wv = { f2bf(wp[0]), f2bf(wp[(size_t)N]), f2bf(wp[(size_t)2 * N]), f2bf(wp[(size_t)3 * N]) };
      *reinterpret_cast<bf16x4*>(&Bs[swz(bnn, kg)]) = wv;
    }
    __syncthreads();
#pragma unroll
    for (int kk = 0; kk < 64; kk += 32) {
      bf16x8 af[4], bfg[4];
#pragma unroll
      for (int mt = 0; mt < 4; ++mt)
        af[mt] = *reinterpret_cast<const bf16x8*>(&As[swz(wr * 64 + mt * 16 + r, kk + g * 8)]);
#pragma unroll
      for (int nt = 0; nt < 4; ++nt)
        bfg[nt] = *reinterpret_cast<const bf16x8*>(&Bs[swz(wc * 64 + nt * 16 + r, kk + g * 8)]);
#pragma unroll
      for (int mt = 0; mt < 4; ++mt)
#pragma unroll
        for (int nt = 0; nt < 4; ++nt)
          acc[mt][nt] = mfma16(af[mt], bfg[nt], acc[mt][nt]);
    }
    __syncthreads();
  }
#pragma unroll
  for (int nt = 0; nt < 4; ++nt) {
    const int col = n0 + wc * 64 + nt * 16 + r;
    const float bv = (EPI == 3) ? 0.f : bias[col];
#pragma unroll
    for (int mt = 0; mt < 4; ++mt) {
#pragma unroll
      for (int j = 0; j < 4; ++j) {
        const int row = m0 + wr * 64 + mt * 16 + 4 * g + j;
        const size_t oi = (size_t)row * N + col;
        float vv = acc[mt][nt][j] + bv;
        if (EPI == 0) {
          ((short*)out)[oi] = f2bf(vv * scale);
        } else if (EPI == 1) {
          vv = 0.5f * vv * (1.f + erff(vv * 0.70710678118654752f));
          ((short*)out)[oi] = f2bf(vv);
        } else if (EPI == 2) {
          ((float*)out)[oi] = resid[oi] + vv;
        } else {
          ((float*)out)[oi] = vv;
        }
      }
    }
  }
}

// ---------- flash-style GQA attention (dbuf, gload_lds staging) ----------
__global__ __launch_bounds__(256) void attn_k(const short* __restrict__ q, int qld,
                                              const short* __restrict__ k, int kld,
                                              const short* __restrict__ vt,
                                              const float* __restrict__ mask,
                                              short* __restrict__ o) {
  __shared__ short Ks[2][64 * 64];  // [s][d], 16B-chunk swizzled
  __shared__ short Vs[2][64 * 64];  // [d][s], 16B-chunk swizzled
  const int t = threadIdx.x, lane = t & 63, w = t >> 6;
  const int g = lane >> 4, r = lane & 15;
  const int h = blockIdx.y, qb = blockIdx.x, kvh = h >> 2;
  const int qrow = qb * 64 + w * 16 + r;

  const short* qp = q + (size_t)qrow * qld + h * 64;
  bf16x8 qf0 = *reinterpret_cast<const bf16x8*>(qp + g * 8);
  bf16x8 qf1 = *reinterpret_cast<const bf16x8*>(qp + 32 + g * 8);

  const short* kbase = k + kvh * 64;                   // + s*kld
  const short* vbase = vt + (size_t)kvh * 64 * 2048;   // + d*2048 + s

  f32x4 oacc[4];
#pragma unroll
  for (int i = 0; i < 4; ++i) { f32x4 z = {0.f, 0.f, 0.f, 0.f}; oacc[i] = z; }
  float m_run = -INFINITY, l_run = 0.f;

  const int srow = w * 8 + (lane >> 3), schunk = lane & 7;

#pragma unroll
  for (int p = 0; p < 2; ++p) {
    const int rr = srow + 32 * p;
    const int cc = (schunk ^ (rr & 7)) << 3;
    gload16(kbase + (size_t)rr * kld + cc, (char*)Ks + p * 4096 + w * 1024);
    gload16(vbase + (size_t)rr * 2048 + cc, (char*)Vs + p * 4096 + w * 1024);
  }
  asm volatile("s_waitcnt vmcnt(0)" ::: "memory");
  __syncthreads();

  for (int it = 0; it < 32; ++it) {
    const int cur = it & 1;
    if (it < 31) {
      const int s1 = (it + 1) * 64;
#pragma unroll
      for (int p = 0; p < 2; ++p) {
        const int rr = srow + 32 * p;
        const int cc = (schunk ^ (rr & 7)) << 3;
        gload16(kbase + (size_t)(s1 + rr) * kld + cc,
                (char*)Ks + (cur ^ 1) * 8192 + p * 4096 + w * 1024);
        gload16(vbase + (size_t)rr * 2048 + s1 + cc,
                (char*)Vs + (cur ^ 1) * 8192 + p * 4096 + w * 1024);
      }
    }
    const int s0 = it * 64;
    const short* Kc = Ks[cur];
    const short* Vc = Vs[cur];

    f32x4 sa[4];
#pragma unroll
    for (int st = 0; st < 4; ++st) {
      bf16x8 kf0 = *reinterpret_cast<const bf16x8*>(&Kc[swz(st * 16 + r, g * 8)]);
      bf16x8 kf1 = *reinterpret_cast<const bf16x8*>(&Kc[swz(st * 16 + r, 32 + g * 8)]);
      f32x4 z = {0.f, 0.f, 0.f, 0.f};
      z = mfma16(kf0, qf0, z);
      z = mfma16(kf1, qf1, z);
      sa[st] = z;
    }
    float sv[16];
    float pmax = -INFINITY;
#pragma unroll
    for (int st = 0; st < 4; ++st) {
      const float4 mv = *reinterpret_cast<const float4*>(mask + s0 + st * 16 + 4 * g);
#pragma unroll
      for (int j = 0; j < 4; ++j) {
        float xx = sa[st][j] + ((const float*)&mv)[j];
        sv[st * 4 + j] = xx;
        pmax = fmaxf(pmax, xx);
      }
    }
    pmax = fmaxf(pmax, __shfl_xor(pmax, 16));
    pmax = fmaxf(pmax, __shfl_xor(pmax, 32));
    float m_new = fmaxf(m_run, pmax);
    float corr = __expf(m_run - m_new);
    float psum = 0.f;
    short pb[16];
#pragma unroll
    for (int i = 0; i < 16; ++i) {
      float p = __expf(sv[i] - m_new);
      psum += p;
      pb[i] = f2bf(p);
    }
    psum += __shfl_xor(psum, 16);
    psum += __shfl_xor(psum, 32);
    l_run = l_run * corr + psum;
    m_run = m_new;
#pragma unroll
    for (int dt = 0; dt < 4; ++dt)
#pragma unroll
      for (int j = 0; j < 4; ++j) oacc[dt][j] *= corr;

#pragma unroll
    for (int hs = 0; hs < 2; ++hs) {
      bf16x8 pf = { pb[hs * 8 + 0], pb[hs * 8 + 1], pb[hs * 8 + 2], pb[hs * 8 + 3],
                    pb[hs * 8 + 4], pb[hs * 8 + 5], pb[hs * 8 + 6], pb[hs * 8 + 7] };
#pragma unroll
      for (int dt = 0; dt < 4; ++dt) {
        int d = dt * 16 + r;
        int c1 = 4 * g + 32 * hs;
        bf16x4 va  = *reinterpret_cast<const bf16x4*>(&Vc[swz(d, c1)]);
        bf16x4 vb2 = *reinterpret_cast<const bf16x4*>(&Vc[swz(d, c1 + 16)]);
        bf16x8 vf = { va[0], va[1], va[2], va[3], vb2[0], vb2[1], vb2[2], vb2[3] };
        oacc[dt] = mfma16(vf, pf, oacc[dt]);
      }
    }
    asm volatile("s_waitcnt vmcnt(0)" ::: "memory");
    __syncthreads();
  }
  float inv = 1.f / l_run;
#pragma unroll
  for (int dt = 0; dt < 4; ++dt) {
    bf16x4 ov = { f2bf(oacc[dt][0] * inv), f2bf(oacc[dt][1] * inv),
                  f2bf(oacc[dt][2] * inv), f2bf(oacc[dt][3] * inv) };
    *reinterpret_cast<bf16x4*>(o + (size_t)qrow * 1024 + h * 64 + dt * 16 + 4 * g) = ov;
  }
}

// ---------- launch ----------
extern "C" void kernel_launch(void* const* d_in, const int* in_sizes, int n_in,
                              void* d_out, int out_size, void* d_ws, size_t ws_size,
                              hipStream_t stream) {
  const int*   ids   = (const int*)d_in[0];
  const float* mask  = (const float*)d_in[1];
  const float* tok   = (const float*)d_in[2];
  const float* pos   = (const float*)d_in[3];
  const float* qW    = (const float*)d_in[4];
  const float* qbias = (const float*)d_in[5];
  const float* kW    = (const float*)d_in[6];
  const float* kbias = (const float*)d_in[7];
  const float* vW    = (const float*)d_in[8];
  const float* vbias = (const float*)d_in[9];
  const float* oW    = (const float*)d_in[10];
  const float* obias = (const float*)d_in[11];
  const float* m1W   = (const float*)d_in[12];
  const float* m1b   = (const float*)d_in[13];
  const float* m2W   = (const float*)d_in[14];
  const float* m2b   = (const float*)d_in[15];
  const float* ln1g  = (const float*)d_in[16];
  const float* ln1b  = (const float*)d_in[17];
  const float* ln2g  = (const float*)d_in[18];
  const float* ln2b  = (const float*)d_in[19];
  const float* lnfg  = (const float*)d_in[20];
  const float* lnfb  = (const float*)d_in[21];
  const float* headW = (const float*)d_in[22];
  float* out = (float*)d_out;

  char* ws = (char*)d_ws;
  float* x   = (float*)ws;                        // 8 MB
  short* xb  = (short*)(ws + 8388608ull);         // 4 MB

  const size_t OFF_QKV  = 12582912ull;   // 6 MB  bf16 [2048][1536]
  const size_t OFF_AO   = 18874368ull;   // 4 MB
  const size_t OFF_FF   = 23068672ull;   // 16 MB (first 1 MB aliased as vt between QKV-GEMM and attn)
  const size_t OFF_BQ   = 39845888ull;   // 24 KB f32 [4][1536]
  const size_t OFF_WQKV = 39870464ull;   // 12 MB bf16 [4][1536][1024]
  const size_t OFF_WO   = 52453376ull;   // 8 MB  bf16 [4][1024][1024]
  const size_t OFF_WM1  = 60841984ull;   // 32 MB bf16 [4][4096][1024]
  const size_t OFF_WM2  = 94396416ull;   // 32 MB bf16 [4][1024][4096]
  const size_t OFF_WH   = 127950848ull;  // 64 MB bf16 [32000][1024]
  const size_t NEED     = 193486848ull;

  if (ws_size >= NEED) {
    short* qkv  = (short*)(ws + OFF_QKV);
    short* ao   = (short*)(ws + OFF_AO);
    short* ff   = (short*)(ws + OFF_FF);
    short* vt   = ff;  // alias: ff dead during QKV->attn window
    float* bqv  = (float*)(ws + OFF_BQ);
    short* Wqkv = (short*)(ws + OFF_WQKV);
    short* Wo   = (short*)(ws + OFF_WO);
    short* Wm1  = (short*)(ws + OFF_WM1);
    short* Wm2  = (short*)(ws + OFF_WM2);
    short* Wh   = (short*)(ws + OFF_WH);

    tcvt_k<<<dim3(16, 8, 4), 256, 0, stream>>>(qW, Wqkv, 1024, 1048576ull, 1572864ull, 0, 1024, 0.125f);
    tcvt_k<<<dim3(4, 8, 4),  256, 0, stream>>>(kW, Wqkv, 256,  262144ull,  1572864ull, 1024, 1024, 1.f);
    tcvt_k<<<dim3(4, 8, 4),  256, 0, stream>>>(vW, Wqkv, 256,  262144ull,  1572864ull, 1280, 1024, 1.f);
    tcvt_k<<<dim3(16, 8, 4), 256, 0, stream>>>(oW, Wo, 1024, 1048576ull, 1048576ull, 0, 1024, 1.f);
    tcvt_k<<<dim3(64, 8, 4), 256, 0, stream>>>(m1W, Wm1, 4096, 4194304ull, 4194304ull, 0, 1024, 1.f);
    tcvt_k<<<dim3(16, 32, 4), 256, 0, stream>>>(m2W, Wm2, 1024, 4194304ull, 4194304ull, 0, 4096, 1.f);
    tcvt_k<<<dim3(500, 8, 1), 256, 0, stream>>>(headW, Wh, 32000, 0ull, 0ull, 0, 1024, 1.f);
    bqkv_k<<<dim3(6, 4), 256, 0, stream>>>(qbias, kbias, vbias, bqv);

    embed_k<<<512, 256, 0, stream>>>(ids, tok, pos, x);

    for (int l = 0; l < 4; ++l) {
      short* Wq_l  = Wqkv + (size_t)l * 1536 * 1024;
      short* Wo_l  = Wo   + (size_t)l * 1024 * 1024;
      short* Wm1_l = Wm1  + (size_t)l * 4096 * 1024;
      short* Wm2_l = Wm2  + (size_t)l * 1024 * 4096;

      ln_k<<<512, 256, 0, stream>>>(x, ln1g + l * 1024, ln1b + l * 1024, xb);
      gemm_bt<4, 0, 1><<<dim3(24, 16), 256, 0, stream>>>(xb, Wq_l, bqv + l * 1536, nullptr,
                                                         qkv, 2048, 1536, 1024, 0, vt);
      attn_k<<<dim3(32, 16), 256, 0, stream>>>(qkv, 1536, qkv + 1024, 1536, vt, mask, ao);
      gemm_bt<2, 0, 1><<<dim3(16, 16), 256, 0, stream>>>(ao, Wo_l, obias + l * 1024, x,
                                                         x, 2048, 1024, 1024, 0, nullptr);
      ln_k<<<512, 256, 0, stream>>>(x, ln2g + l * 1024, ln2b + l * 1024, xb);
      gemm_bt<1, 1, 1><<<dim3(64, 16), 256, 0, stream>>>(xb, Wm1_l, m1b + l * 4096, nullptr,
                                                         ff, 2048, 4096, 1024, 0, nullptr);
      gemm_bt<2, 1, 1><<<dim3(16, 16), 256, 0, stream>>>(ff, Wm2_l, m2b + l * 1024, x,
                                                         x, 2048, 1024, 4096, 0, nullptr);
    }
    ln_k<<<512, 256, 0, stream>>>(x, lnfg, lnfb, xb);
    gemm_bt<3, 1, 0><<<dim3(125, 16), 256, 0, stream>>>(xb, Wh, nullptr, nullptr,
                                                        out, 2048, 32000, 1024, 0, nullptr);
    gemm_bt<3, 1, 0><<<dim3(125, 16), 256, 0, stream>>>(xb, Wh, nullptr, nullptr,
                                                        out, 2048, 32000, 1024, 125, nullptr);
  } else {
    // fallback: f32-weight GEMMs, needs < 40 MB ws
    short* qbf = (short*)(ws + (12u << 20));
    short* kbf = (short*)(ws + (16u << 20));
    short* vbf = (short*)(ws + (17u << 20));
    short* ao  = (short*)(ws + (18u << 20));
    short* ff  = (short*)(ws + (22u << 20));
    short* vtf = (short*)(ws + (38u << 20));

    embed_k<<<512, 256, 0, stream>>>(ids, tok, pos, x);
    for (int l = 0; l < 4; ++l) {
      ln_k<<<512, 256, 0, stream>>>(x, ln1g + l * 1024, ln1b + l * 1024, xb);
      gemm_k<0><<<dim3(8, 16), 256, 0, stream>>>(xb, qW + (size_t)l * 1024 * 1024,
          qbias + l * 1024, nullptr, qbf, 2048, 1024, 1024, 0.125f);
      gemm_k<0><<<dim3(2, 16), 256, 0, stream>>>(xb, kW + (size_t)l * 1024 * 256,
          kbias + l * 256, nullptr, kbf, 2048, 256, 1024, 1.f);
      gemm_k<0><<<dim3(2, 16), 256, 0, stream>>>(xb, vW + (size_t)l * 1024 * 256,
          vbias + l * 256, nullptr, vbf, 2048, 256, 1024, 1.f);
      vtr_k<<<dim3(32, 4), 256, 0, stream>>>(vbf, 256, vtf);
      attn_k<<<dim3(32, 16), 256, 0, stream>>>(qbf, 1024, kbf, 256, vtf, mask, ao);
      gemm_k<2><<<dim3(8, 16), 256, 0, stream>>>(ao, oW + (size_t)l * 1024 * 1024,
          obias + l * 1024, x, x, 2048, 1024, 1024, 1.f);
      ln_k<<<512, 256, 0, stream>>>(x, ln2g + l * 1024, ln2b + l * 1024, xb);
      gemm_k<1><<<dim3(32, 16), 256, 0, stream>>>(xb, m1W + (size_t)l * 1024 * 4096,
          m1b + l * 4096, nullptr, ff, 2048, 4096, 1024, 1.f);
      gemm_k<2><<<dim3(8, 16), 256, 0, stream>>>(ff, m2W + (size_t)l * 4096 * 1024,
          m2b + l * 1024, x, x, 2048, 1024, 4096, 1.f);
    }
    ln_k<<<512, 256, 0, stream>>>(x, lnfg, lnfb, xb);
    gemm_k<3><<<dim3(250, 16), 256, 0, stream>>>(xb, headW, nullptr, nullptr, out,
        2048, 32000, 1024, 1.f);
  }
}